// Round 15
// baseline (534.292 us; speedup 1.0000x reference)
//
#include <hip/hip_runtime.h>

typedef __attribute__((ext_vector_type(8))) _Float16 f16x8;
typedef __attribute__((ext_vector_type(4))) _Float16 f16x4;
typedef __attribute__((ext_vector_type(4))) float f32x4;

#define DI __device__ __forceinline__
// Raw barrier: LDS-drain only (lgkmcnt).
#define BAR() asm volatile("s_waitcnt lgkmcnt(0)\n\ts_barrier" ::: "memory")
// Barrier that also drains VMEM (for global_load_lds completion).
#define BARV() asm volatile("s_waitcnt vmcnt(0) lgkmcnt(0)\n\ts_barrier" ::: "memory")

DI f32x4 mfma16(f16x8 a, f16x8 b, f32x4 c) {
    return __builtin_amdgcn_mfma_f32_16x16x32_f16(a, b, c, 0, 0, 0);
}

DI void glds16(const void* g, void* l) {
    __builtin_amdgcn_global_load_lds(
        (const __attribute__((address_space(1))) void*)g,
        (__attribute__((address_space(3))) void*)l, 16, 0, 0);
}

// Wave-mapping: wave w owns features [w*32, w*32+32) for layers 0/1 (2 n-tiles,
// weight frags reused across all MH m-groups of 16 rows). Layer 2: wave w computes
// rows (w>>1)*16 (+32*g) and cols (w&1)*16 of the MHx16 x 32 output.
// PROVEN: lb(256,3); resident weights need ~150 regs/wave -> never cap at 4/EU.
// R14 lesson: glds staging MUST use prefetched sr addresses (dependent sr->glds
// chain mid-loop costs more than the async overlap gains).

template <int NK>
DI void load_wf2(const _Float16* __restrict__ wt, int Kp, int nbase, int l16, int q,
                 f16x8 f[NK][2]) {
#pragma unroll
    for (int nt = 0; nt < 2; ++nt) {
        int n = nbase + nt * 16 + l16;
#pragma unroll
        for (int ks = 0; ks < NK; ++ks)
            f[ks][nt] = *(const f16x8*)(wt + n * Kp + ks * 32 + q * 8);
    }
}

// Layer 0: X(stride xstride) -> relu -> H0 (stride 136).
template <int NK0, int MH>
DI void l0_run(const f16x8 (*w0f)[2], const _Float16* __restrict__ X, int xstride,
               _Float16* __restrict__ H0, int l16, int w, int q) {
    const f32x4 zero = {0.f, 0.f, 0.f, 0.f};
    f32x4 acc[2][MH];
#pragma unroll
    for (int nt = 0; nt < 2; ++nt)
#pragma unroll
        for (int mt = 0; mt < MH; ++mt) acc[nt][mt] = zero;
#pragma unroll
    for (int ks = 0; ks < NK0; ++ks) {
        f16x8 x[MH];
#pragma unroll
        for (int mt = 0; mt < MH; ++mt)
            x[mt] = *(const f16x8*)(X + (mt * 16 + l16) * xstride + ks * 32 + q * 8);
#pragma unroll
        for (int nt = 0; nt < 2; ++nt)
#pragma unroll
            for (int mt = 0; mt < MH; ++mt)
                acc[nt][mt] = mfma16(w0f[ks][nt], x[mt], acc[nt][mt]);
    }
#pragma unroll
    for (int mt = 0; mt < MH; ++mt)
#pragma unroll
        for (int nt = 0; nt < 2; ++nt) {
            f16x4 h;
#pragma unroll
            for (int i = 0; i < 4; ++i) h[i] = (_Float16)fmaxf(acc[nt][mt][i], 0.f);
            *(f16x4*)(H0 + (mt * 16 + l16) * 136 + w * 32 + nt * 16 + q * 4) = h;
        }
}

// Layer 1: H0 -> relu -> H1 (both stride 136).
template <int MH>
DI void l1_run(const f16x8 (*w1f)[2], const _Float16* __restrict__ H0,
               _Float16* __restrict__ H1, int l16, int w, int q) {
    const f32x4 zero = {0.f, 0.f, 0.f, 0.f};
    f32x4 a1[2][MH];
#pragma unroll
    for (int nt = 0; nt < 2; ++nt)
#pragma unroll
        for (int mt = 0; mt < MH; ++mt) a1[nt][mt] = zero;
#pragma unroll
    for (int ks = 0; ks < 4; ++ks) {
        f16x8 x[MH];
#pragma unroll
        for (int mt = 0; mt < MH; ++mt)
            x[mt] = *(const f16x8*)(H0 + (mt * 16 + l16) * 136 + ks * 32 + q * 8);
#pragma unroll
        for (int nt = 0; nt < 2; ++nt)
#pragma unroll
            for (int mt = 0; mt < MH; ++mt)
                a1[nt][mt] = mfma16(w1f[ks][nt], x[mt], a1[nt][mt]);
    }
#pragma unroll
    for (int mt = 0; mt < MH; ++mt)
#pragma unroll
        for (int nt = 0; nt < 2; ++nt) {
            f16x4 h;
#pragma unroll
            for (int i = 0; i < 4; ++i) h[i] = (_Float16)fmaxf(a1[nt][mt][i], 0.f);
            *(f16x4*)(H1 + (mt * 16 + l16) * 136 + w * 32 + nt * 16 + q * 4) = h;
        }
}

// Combined layers 0+1 (used by k_enc / k_node / k_dec).
template <int NK0, int MH>
DI void l01(const f16x8 (*w0f)[2], const f16x8 (*w1f)[2],
            const _Float16* __restrict__ X, int xstride,
            _Float16* __restrict__ H0, _Float16* __restrict__ H1,
            int l16, int w, int q) {
    l0_run<NK0, MH>(w0f, X, xstride, H0, l16, w, q);
    BAR();
    l1_run<MH>(w1f, H0, H1, l16, w, q);
    BAR();
}

// Layer 2, row group g: rows (w>>1)*16 + l16 + 32*g, cols (w&1)*16 + q*4 + i.
DI f32x4 l2g(const f16x8* w2f, const _Float16* __restrict__ H1, int l16, int w,
             int q, int g) {
    int m = (w >> 1) * 16 + l16 + 32 * g;
    f32x4 acc = {0.f, 0.f, 0.f, 0.f};
#pragma unroll
    for (int ks = 0; ks < 4; ++ks) {
        f16x8 x = *(const f16x8*)(H1 + m * 136 + ks * 32 + q * 8);
        acc = mfma16(w2f[ks], x, acc);
    }
    return acc;
}

// ---------------- weight prep: fp32 [K][N] -> f16 W^T [Np][Kp] (zero padded) ----
struct WPtrs { const float* p[15]; };

__global__ void k_prep(WPtrs wp, _Float16* __restrict__ ws) {
    int b = blockIdx.x;
    const float* src; int K, N, Np, Kp, off;
    if (b == 0)       { src = wp.p[0];  K = 3;   N = 128; Np = 128; Kp = 32;  off = 0; }
    else if (b == 1)  { src = wp.p[1];  K = 128; N = 128; Np = 128; Kp = 128; off = 4096; }
    else if (b == 2)  { src = wp.p[2];  K = 128; N = 32;  Np = 32;  Kp = 128; off = 20480; }
    else if (b == 3)  { src = wp.p[3];  K = 3;   N = 128; Np = 128; Kp = 32;  off = 24576; }
    else if (b == 4)  { src = wp.p[4];  K = 128; N = 128; Np = 128; Kp = 128; off = 28672; }
    else if (b == 5)  { src = wp.p[5];  K = 128; N = 32;  Np = 32;  Kp = 128; off = 45056; }
    else if (b <= 9)  { int t = b - 6;  src = wp.p[6] + t * 12288;  K = 96;  N = 128; Np = 128; Kp = 96;  off = 49152 + t * 32768; }
    else if (b <= 13) { int t = b - 10; src = wp.p[7] + t * 16384;  K = 128; N = 128; Np = 128; Kp = 128; off = 61440 + t * 32768; }
    else if (b <= 17) { int t = b - 14; src = wp.p[8] + t * 4096;   K = 128; N = 32;  Np = 32;  Kp = 128; off = 77824 + t * 32768; }
    else if (b <= 21) { int t = b - 18; src = wp.p[9] + t * 8192;   K = 64;  N = 128; Np = 128; Kp = 64;  off = 180224 + t * 28672; }
    else if (b <= 25) { int t = b - 22; src = wp.p[10] + t * 16384; K = 128; N = 128; Np = 128; Kp = 128; off = 188416 + t * 28672; }
    else if (b <= 29) { int t = b - 26; src = wp.p[11] + t * 4096;  K = 128; N = 32;  Np = 32;  Kp = 128; off = 204800 + t * 28672; }
    else if (b == 30) { src = wp.p[12]; K = 32;  N = 128; Np = 128; Kp = 32;  off = 294912; }
    else if (b == 31) { src = wp.p[13]; K = 128; N = 128; Np = 128; Kp = 128; off = 299008; }
    else              { src = wp.p[14]; K = 128; N = 1;   Np = 16;  Kp = 128; off = 315392; }
    int total = Np * Kp;
    for (int i = threadIdx.x; i < total; i += 256) {
        int n = i / Kp, k = i - n * Kp;
        float v = (k < K && n < N) ? src[k * N + n] : 0.f;
        ws[off + i] = (_Float16)v;
    }
}

// ---------------- CSR build: histogram -> scan -> scatter (u32 atomics only) -----
__global__ void k_zero(unsigned* __restrict__ p, int n) {
    int i = blockIdx.x * 256 + threadIdx.x;
    if (i < n) p[i] = 0u;
}
__global__ void k_hist(const int* __restrict__ gi, unsigned* __restrict__ cnt) {
    int e = blockIdx.x * 256 + threadIdx.x;
    if (e < 512000) atomicAdd(&cnt[gi[2 * e + 1]], 1u);
}
// one block, 1024 threads: exclusive scan of cnt[0..32000) via Kogge-Stone.
__global__ __launch_bounds__(1024) void k_scan(
    const unsigned* __restrict__ cnt, unsigned* __restrict__ rowptr,
    unsigned* __restrict__ cursor) {
    __shared__ unsigned s[1024];
    int t = threadIdx.x;
    unsigned loc[32];
    unsigned sum = 0;
#pragma unroll
    for (int i = 0; i < 32; ++i) {
        int idx = t * 32 + i;
        unsigned v = (idx < 32000) ? cnt[idx] : 0u;
        loc[i] = v; sum += v;
    }
    s[t] = sum;
    __syncthreads();
#pragma unroll
    for (int d = 1; d < 1024; d <<= 1) {
        unsigned x = (t >= d) ? s[t - d] : 0u;
        __syncthreads();
        s[t] += x;
        __syncthreads();
    }
    if (t == 1023) rowptr[32000] = s[1023];
    unsigned off = (t == 0) ? 0u : s[t - 1];
#pragma unroll
    for (int i = 0; i < 32; ++i) {
        int idx = t * 32 + i;
        if (idx < 32000) { rowptr[idx] = off; cursor[idx] = off; off += loc[i]; }
    }
}
__global__ void k_scatter(const int* __restrict__ gi, unsigned* __restrict__ cursor,
                          unsigned* __restrict__ iperm, int2* __restrict__ sr) {
    int e = blockIdx.x * 256 + threadIdx.x;
    if (e < 512000) {
        int s = gi[2 * e], r = gi[2 * e + 1];
        unsigned pos = atomicAdd(&cursor[r], 1u);
        iperm[pos] = (unsigned)e;
        sr[pos] = make_int2(s, r);
    }
}

// ---------------- encoder: fp32 [M][3] -> MLP -> f16 out rows (64-row tiles) -----
__global__ __launch_bounds__(256, 3) void k_enc(
    const float* __restrict__ in, _Float16* __restrict__ out,
    const _Float16* __restrict__ w0t, const _Float16* __restrict__ w1t,
    const _Float16* __restrict__ w2t, int NT, const unsigned* __restrict__ iperm) {
    __shared__ __align__(16) _Float16 Xp[64 * 40];
    __shared__ __align__(16) _Float16 H0[64 * 136];
    __shared__ __align__(16) _Float16 H1[64 * 136];
    const int tid = threadIdx.x, w = tid >> 6, lane = tid & 63;
    const int q = lane >> 4, l16 = lane & 15;
    f16x8 w0f[1][2], w1f[4][2], w2f[4];
    load_wf2<1>(w0t, 32, w * 32, l16, q, w0f);
    load_wf2<4>(w1t, 128, w * 32, l16, q, w1f);
    {
        int n2 = (w & 1) * 16 + l16;
#pragma unroll
        for (int ks = 0; ks < 4; ++ks)
            w2f[ks] = *(const f16x8*)(w2t + n2 * 128 + ks * 32 + q * 8);
    }
    for (int c = tid; c < 2560; c += 256) Xp[c] = (_Float16)0.f;
    BAR();

    const int g = gridDim.x;
    const int dr = tid / 3, dc = tid - dr * 3;  // valid when tid<192
    const int orow = (w >> 1) * 16 + l16, ocol = (w & 1) * 16 + q * 4;
    int t = blockIdx.x;

    while (true) {
        if (tid < 192) {
            unsigned e = iperm ? iperm[t * 64 + dr] : (unsigned)(t * 64 + dr);
            Xp[dr * 40 + dc] = (_Float16)in[e * 3 + dc];
        }
        BAR();
        l01<1, 4>(w0f, w1f, Xp, 40, H0, H1, l16, w, q);
#pragma unroll
        for (int gg = 0; gg < 2; ++gg) {
            f32x4 o = l2g(w2f, H1, l16, w, q, gg);
            f16x4 ov;
#pragma unroll
            for (int i = 0; i < 4; ++i) ov[i] = (_Float16)o[i];
            *(f16x4*)(out + (t * 64 + gg * 32 + orow) * 32 + ocol) = ov;
        }
        t += g;
        if (t >= NT) break;
    }
}

// ---------------- edge update: [edge|node_s|node_r](96) -> MLP -> +res -----------
// 64-row tiles, f16 latents, receiver-sorted rows. Async glds staging into Xe
// (13 16-B slots/row: 12 real + 1 pad -> stride 104 f16) with sr addresses
// PREFETCHED one tile ahead, so stage() issues with zero waits and the gather
// overlaps l1+l2. Loop-top barrier drains vmcnt.
__global__ __launch_bounds__(256, 3) void k_edge(
    const _Float16* __restrict__ node, _Float16* __restrict__ edgeP,
    const int2* __restrict__ sr,
    const _Float16* __restrict__ w0t, const _Float16* __restrict__ w1t,
    const _Float16* __restrict__ w2t) {
    __shared__ __align__(16) _Float16 Xe[64 * 104];  // 832 slots x 16 B
    __shared__ __align__(16) _Float16 H0[64 * 136];
    __shared__ __align__(16) _Float16 H1[64 * 136];
    const int tid = threadIdx.x, w = tid >> 6, lane = tid & 63;
    const int q = lane >> 4, l16 = lane & 15;
    f16x8 w0f[3][2], w1f[4][2], w2f[4];
    load_wf2<3>(w0t, 96, w * 32, l16, q, w0f);
    load_wf2<4>(w1t, 128, w * 32, l16, q, w1f);
    {
        int n2 = (w & 1) * 16 + l16;
#pragma unroll
        for (int ks = 0; ks < 4; ++ks)
            w2f[ks] = *(const f16x8*)(w2t + n2 * 128 + ks * 32 + q * 8);
    }
    // slot s = 256*i + tid -> row m = s/13 (magic mul), chunk cc = s%13.
    int sm[4], sc[4];
#pragma unroll
    for (int i = 0; i < 4; ++i) {
        int s = 256 * i + tid;
        int m = (s * 5042) >> 16;  // exact floor(s/13) for s < 832
        sm[i] = m; sc[i] = s - m * 13;
    }
    const int orow = (w >> 1) * 16 + l16, ocol = (w & 1) * 16 + q * 4;
    const int NT = 8000, g = gridDim.x;

    // stage(tile, addrs): issue 16-B async loads for all 832 slots; addresses
    // come from pre-loaded sv[] so no vmcnt wait is needed at issue time.
    auto stage = [&](int tt, const int2* sv) {
#pragma unroll
        for (int i = 0; i < 4; ++i) {
            if (i < 3 || tid < 64) {
                int m = sm[i], cc = sc[i];
                const _Float16* src;
                if (cc < 4)       src = edgeP + (tt * 64 + m) * 32 + cc * 8;
                else if (cc < 8)  src = node + sv[i].x * 32 + (cc - 4) * 8;
                else if (cc < 12) src = node + sv[i].y * 32 + (cc - 8) * 8;
                else              src = edgeP + (tt * 64 + m) * 32;  // pad slot
                glds16(src, Xe + (i * 256 + w * 64) * 8);
            }
        }
    };

    int t = blockIdx.x;
    int tn = t + g; if (tn >= NT) tn = t;
    int2 srv[4], srn[4];
#pragma unroll
    for (int i = 0; i < 4; ++i)
        if (i < 3 || tid < 64) srv[i] = sr[t * 64 + sm[i]];
    stage(t, srv);
#pragma unroll
    for (int i = 0; i < 4; ++i)
        if (i < 3 || tid < 64) srn[i] = sr[tn * 64 + sm[i]];

    while (true) {
        BARV();  // Xe(t) complete block-wide
        f16x4 oldv[2];
#pragma unroll
        for (int gg = 0; gg < 2; ++gg)
            oldv[gg] = *(const f16x4*)(Xe + (gg * 32 + orow) * 104 + ocol);
        l0_run<3, 4>(w0f, Xe, 104, H0, l16, w, q);
        BAR();   // Xe dead, H0 ready
        int tn2 = tn + g; if (tn2 >= NT) tn2 = tn;
        if (tn != t) stage(tn, srn);  // zero-wait issue; overlaps l1 + l2
        int2 sr2[4];
#pragma unroll
        for (int i = 0; i < 4; ++i)
            if (i < 3 || tid < 64) sr2[i] = sr[tn2 * 64 + sm[i]];
        l1_run<4>(w1f, H0, H1, l16, w, q);
        BAR();   // H1 ready
#pragma unroll
        for (int gg = 0; gg < 2; ++gg) {
            f32x4 o = l2g(w2f, H1, l16, w, q, gg);
            f16x4 nv;
#pragma unroll
            for (int i = 0; i < 4; ++i) nv[i] = (_Float16)(o[i] + (float)oldv[gg][i]);
            *(f16x4*)(edgeP + (t * 64 + gg * 32 + orow) * 32 + ocol) = nv;
        }
        if (tn == t) break;
        t = tn; tn = tn2;
#pragma unroll
        for (int i = 0; i < 4; ++i) srn[i] = sr2[i];
    }
}

// ---------------- node update: [node|csr_sum(edgeP)](64) -> MLP -> +res ----------
// Proven 32-row data path; 2-iteration grid-stride loop halves per-block fixed
// weight-load cost. Safety: after l01's first internal barrier no wave reads Xn,
// so next iteration's staging (post final-BAR, pre stage-BAR) cannot race.
__global__ __launch_bounds__(256, 3) void k_node(
    _Float16* __restrict__ node, const _Float16* __restrict__ edgeP,
    const unsigned* __restrict__ rowptr,
    const _Float16* __restrict__ w0t, const _Float16* __restrict__ w1t,
    const _Float16* __restrict__ w2t) {
    __shared__ __align__(16) _Float16 Xn[32 * 72];
    __shared__ __align__(16) _Float16 H0[32 * 136];
    __shared__ __align__(16) _Float16 H1[32 * 136];
    const int tid = threadIdx.x, w = tid >> 6, lane = tid & 63;
    const int q = lane >> 4, l16 = lane & 15;
    f16x8 w0f[2][2], w1f[4][2], w2f[4];
    load_wf2<2>(w0t, 64, w * 32, l16, q, w0f);
    load_wf2<4>(w1t, 128, w * 32, l16, q, w1f);
    {
        int n2 = (w & 1) * 16 + l16;
#pragma unroll
        for (int ks = 0; ks < 4; ++ks)
            w2f[ks] = *(const f16x8*)(w2t + n2 * 128 + ks * 32 + q * 8);
    }
    const int orow = (w >> 1) * 16 + l16, ocol = (w & 1) * 16 + q * 4;
    const int g = gridDim.x;
    for (int t = blockIdx.x; t < 1000; t += g) {
        // 8 chunks/row (16 B each): cs<4 node copy, cs>=4 segment-sum of edgeP chunk
        {
            int cr = tid >> 3, cs = tid & 7;
            int r = t * 32 + cr;
            if (cs < 4) {
                *(int4*)(Xn + cr * 72 + cs * 8) = *(const int4*)(node + r * 32 + cs * 8);
            } else {
                unsigned b = rowptr[r], e = rowptr[r + 1];
                const _Float16* base = edgeP + (cs - 4) * 8;
                float a0[8], a1[8];
#pragma unroll
                for (int i = 0; i < 8; ++i) { a0[i] = 0.f; a1[i] = 0.f; }
                unsigned p = b;
                for (; p + 2 <= e; p += 2) {
                    f16x8 x0 = *(const f16x8*)(base + (p + 0) * 32);
                    f16x8 x1 = *(const f16x8*)(base + (p + 1) * 32);
#pragma unroll
                    for (int i = 0; i < 8; ++i) { a0[i] += (float)x0[i]; a1[i] += (float)x1[i]; }
                }
                if (p < e) {
                    f16x8 x0 = *(const f16x8*)(base + p * 32);
#pragma unroll
                    for (int i = 0; i < 8; ++i) a0[i] += (float)x0[i];
                }
                f16x8 h;
#pragma unroll
                for (int i = 0; i < 8; ++i) h[i] = (_Float16)(a0[i] + a1[i]);
                *(f16x8*)(Xn + cr * 72 + cs * 8) = h;
            }
        }
        BAR();
        f16x4 oldv = *(const f16x4*)(Xn + orow * 72 + ocol);
        l01<2, 2>(w0f, w1f, Xn, 72, H0, H1, l16, w, q);
        f32x4 o = l2g(w2f, H1, l16, w, q, 0);
        f16x4 nv;
#pragma unroll
        for (int i = 0; i < 4; ++i) nv[i] = (_Float16)(o[i] + (float)oldv[i]);
        *(f16x4*)(node + (t * 32 + orow) * 32 + ocol) = nv;
    }
}

// ---------------- decoder: node(32) -> MLP(32->128->128->1) -> fp32 out ----------
__global__ __launch_bounds__(256, 3) void k_dec(
    const _Float16* __restrict__ node,
    const _Float16* __restrict__ w0t, const _Float16* __restrict__ w1t,
    const _Float16* __restrict__ w2t, float* __restrict__ out) {
    __shared__ __align__(16) _Float16 Xd[64 * 40];
    __shared__ __align__(16) _Float16 H0[64 * 136];
    __shared__ __align__(16) _Float16 H1[64 * 136];
    const int tid = threadIdx.x, w = tid >> 6, lane = tid & 63;
    const int q = lane >> 4, l16 = lane & 15;
    f16x8 w0f[1][2], w1f[4][2], w2f[4];
    load_wf2<1>(w0t, 32, w * 32, l16, q, w0f);
    load_wf2<4>(w1t, 128, w * 32, l16, q, w1f);
    {
        int n2 = l16;  // padded W2^T is [16][128]; all waves load tile 0
#pragma unroll
        for (int ks = 0; ks < 4; ++ks)
            w2f[ks] = *(const f16x8*)(w2t + n2 * 128 + ks * 32 + q * 8);
    }
    const int t = blockIdx.x;
    {
        int cr = tid >> 2, cs = tid & 3;
        *(int4*)(Xd + cr * 40 + cs * 8) = *(const int4*)(node + (t * 64 + cr) * 32 + cs * 8);
    }
    BAR();
    l01<1, 4>(w0f, w1f, Xd, 40, H0, H1, l16, w, q);
#pragma unroll
    for (int gg = 0; gg < 2; ++gg) {
        f32x4 o = l2g(w2f, H1, l16, w, q, gg);
        // only col 0 is real: waves with (w&1)==0, lanes q==0, reg 0
        if ((w & 1) == 0 && q == 0) out[t * 64 + gg * 32 + (w >> 1) * 16 + l16] = o[0];
    }
}

extern "C" void kernel_launch(void* const* d_in, const int* in_sizes, int n_in,
                              void* d_out, int out_size, void* d_ws, size_t ws_size,
                              hipStream_t stream) {
    const float* input_node = (const float*)d_in[0];
    const float* input_edge = (const float*)d_in[1];
    const int* gi = (const int*)d_in[2];

    _Float16* ws = (_Float16*)d_ws;
    // ws layout (bytes):
    //   weights f16:         [0,          634,880)
    //   node  f16 32000x32:  [655,360,    2,703,360)
    //   edgeP f16 512000x32: [2,703,360,  35,471,360)   (receiver-sorted rows)
    //   rowptr u32[32001]:   [35,471,360, 35,599,364)
    //   cursor u32[32000]:   [35,599,616, 35,727,616)
    //   iperm  u32[512000]:  [35,727,616, 37,775,616)
    //   sr   int2[512000]:   [37,775,616, 41,871,616)
    _Float16* node = (_Float16*)((char*)d_ws + 655360);
    _Float16* edgeP = (_Float16*)((char*)d_ws + 2703360);
    unsigned* rowptr = (unsigned*)((char*)d_ws + 35471360);
    unsigned* cursor = (unsigned*)((char*)d_ws + 35599616);
    unsigned* iperm = (unsigned*)((char*)d_ws + 35727616);
    int2* sr = (int2*)((char*)d_ws + 37775616);

    WPtrs wp;
    for (int i = 0; i < 15; ++i) wp.p[i] = (const float*)d_in[3 + i];

    k_prep<<<33, 256, 0, stream>>>(wp, ws);

    // CSR build (u32 atomics only)
    k_zero<<<125, 256, 0, stream>>>(cursor, 32000);
    k_hist<<<2000, 256, 0, stream>>>(gi, cursor);
    k_scan<<<1, 1024, 0, stream>>>(cursor, rowptr, cursor);
    k_scatter<<<2000, 256, 0, stream>>>(gi, cursor, iperm, sr);

    k_enc<<<500, 256, 0, stream>>>(input_node, node, ws + 0, ws + 4096, ws + 20480,
                                   500, nullptr);
    k_enc<<<768, 256, 0, stream>>>(input_edge, edgeP, ws + 24576, ws + 28672,
                                   ws + 45056, 8000, iperm);

    for (int t = 0; t < 4; ++t) {
        k_edge<<<768, 256, 0, stream>>>(node, edgeP, sr,
                                        ws + 49152 + t * 32768,
                                        ws + 61440 + t * 32768,
                                        ws + 77824 + t * 32768);
        k_node<<<500, 256, 0, stream>>>(node, edgeP, rowptr,
                                        ws + 180224 + t * 28672,
                                        ws + 188416 + t * 28672,
                                        ws + 204800 + t * 28672);
    }
    k_dec<<<500, 256, 0, stream>>>(node, ws + 294912, ws + 299008, ws + 315392,
                                   (float*)d_out);
}

// Round 16
// 509.104 us; speedup vs baseline: 1.0495x; 1.0495x over previous
//
#include <hip/hip_runtime.h>

typedef __attribute__((ext_vector_type(8))) _Float16 f16x8;
typedef __attribute__((ext_vector_type(4))) _Float16 f16x4;
typedef __attribute__((ext_vector_type(4))) float f32x4;

#define DI __device__ __forceinline__
// Raw barrier: LDS-drain only (lgkmcnt). Avoids the compiler's vmcnt(0) drain.
#define BAR() asm volatile("s_waitcnt lgkmcnt(0)\n\ts_barrier" ::: "memory")

DI f32x4 mfma16(f16x8 a, f16x8 b, f32x4 c) {
    return __builtin_amdgcn_mfma_f32_16x16x32_f16(a, b, c, 0, 0, 0);
}

// Wave-mapping: wave w owns features [w*32, w*32+32) for layers 0/1 (2 n-tiles,
// weight frags reused across all MH m-groups of 16 rows). Layer 2: wave w computes
// rows (w>>1)*16 (+32*g) and cols (w&1)*16 of the MHx16 x 32 output.
// PROVEN (R13, 504 us): lb(256,3), register staging in k_edge, sr one tile ahead.
// Failed levers (do not retry): lb(256,4) [spills weights], explicit data
// pipeline [spills], glds async staging [R14/R15: slower], 64-row MH=4 k_node
// [R12: diverges under graph replay].

template <int NK>
DI void load_wf2(const _Float16* __restrict__ wt, int Kp, int nbase, int l16, int q,
                 f16x8 f[NK][2]) {
#pragma unroll
    for (int nt = 0; nt < 2; ++nt) {
        int n = nbase + nt * 16 + l16;
#pragma unroll
        for (int ks = 0; ks < NK; ++ks)
            f[ks][nt] = *(const f16x8*)(wt + n * Kp + ks * 32 + q * 8);
    }
}

// Layers 0/1 over MH 16-row groups: D' = W^T X^T; relu'd f16 to H (stride 136).
template <int NK0, int MH>
DI void l01(const f16x8 (*w0f)[2], const f16x8 (*w1f)[2],
            const _Float16* __restrict__ X, int xstride,
            _Float16* __restrict__ H0, _Float16* __restrict__ H1,
            int l16, int w, int q) {
    const f32x4 zero = {0.f, 0.f, 0.f, 0.f};
    f32x4 acc[2][MH];
#pragma unroll
    for (int nt = 0; nt < 2; ++nt)
#pragma unroll
        for (int mt = 0; mt < MH; ++mt) acc[nt][mt] = zero;
#pragma unroll
    for (int ks = 0; ks < NK0; ++ks) {
        f16x8 x[MH];
#pragma unroll
        for (int mt = 0; mt < MH; ++mt)
            x[mt] = *(const f16x8*)(X + (mt * 16 + l16) * xstride + ks * 32 + q * 8);
#pragma unroll
        for (int nt = 0; nt < 2; ++nt)
#pragma unroll
            for (int mt = 0; mt < MH; ++mt)
                acc[nt][mt] = mfma16(w0f[ks][nt], x[mt], acc[nt][mt]);
    }
#pragma unroll
    for (int mt = 0; mt < MH; ++mt)
#pragma unroll
        for (int nt = 0; nt < 2; ++nt) {
            f16x4 h;
#pragma unroll
            for (int i = 0; i < 4; ++i) h[i] = (_Float16)fmaxf(acc[nt][mt][i], 0.f);
            *(f16x4*)(H0 + (mt * 16 + l16) * 136 + w * 32 + nt * 16 + q * 4) = h;
        }
    BAR();
    f32x4 a1[2][MH];
#pragma unroll
    for (int nt = 0; nt < 2; ++nt)
#pragma unroll
        for (int mt = 0; mt < MH; ++mt) a1[nt][mt] = zero;
#pragma unroll
    for (int ks = 0; ks < 4; ++ks) {
        f16x8 x[MH];
#pragma unroll
        for (int mt = 0; mt < MH; ++mt)
            x[mt] = *(const f16x8*)(H0 + (mt * 16 + l16) * 136 + ks * 32 + q * 8);
#pragma unroll
        for (int nt = 0; nt < 2; ++nt)
#pragma unroll
            for (int mt = 0; mt < MH; ++mt)
                a1[nt][mt] = mfma16(w1f[ks][nt], x[mt], a1[nt][mt]);
    }
#pragma unroll
    for (int mt = 0; mt < MH; ++mt)
#pragma unroll
        for (int nt = 0; nt < 2; ++nt) {
            f16x4 h;
#pragma unroll
            for (int i = 0; i < 4; ++i) h[i] = (_Float16)fmaxf(a1[nt][mt][i], 0.f);
            *(f16x4*)(H1 + (mt * 16 + l16) * 136 + w * 32 + nt * 16 + q * 4) = h;
        }
    BAR();
}

// Layer 2, row group g: rows (w>>1)*16 + l16 + 32*g, cols (w&1)*16 + q*4 + i.
DI f32x4 l2g(const f16x8* w2f, const _Float16* __restrict__ H1, int l16, int w,
             int q, int g) {
    int m = (w >> 1) * 16 + l16 + 32 * g;
    f32x4 acc = {0.f, 0.f, 0.f, 0.f};
#pragma unroll
    for (int ks = 0; ks < 4; ++ks) {
        f16x8 x = *(const f16x8*)(H1 + m * 136 + ks * 32 + q * 8);
        acc = mfma16(w2f[ks], x, acc);
    }
    return acc;
}

// ---------------- weight prep: fp32 [K][N] -> f16 W^T [Np][Kp] (zero padded) ----
struct WPtrs { const float* p[15]; };

__global__ void k_prep(WPtrs wp, _Float16* __restrict__ ws) {
    int b = blockIdx.x;
    const float* src; int K, N, Np, Kp, off;
    if (b == 0)       { src = wp.p[0];  K = 3;   N = 128; Np = 128; Kp = 32;  off = 0; }
    else if (b == 1)  { src = wp.p[1];  K = 128; N = 128; Np = 128; Kp = 128; off = 4096; }
    else if (b == 2)  { src = wp.p[2];  K = 128; N = 32;  Np = 32;  Kp = 128; off = 20480; }
    else if (b == 3)  { src = wp.p[3];  K = 3;   N = 128; Np = 128; Kp = 32;  off = 24576; }
    else if (b == 4)  { src = wp.p[4];  K = 128; N = 128; Np = 128; Kp = 128; off = 28672; }
    else if (b == 5)  { src = wp.p[5];  K = 128; N = 32;  Np = 32;  Kp = 128; off = 45056; }
    else if (b <= 9)  { int t = b - 6;  src = wp.p[6] + t * 12288;  K = 96;  N = 128; Np = 128; Kp = 96;  off = 49152 + t * 32768; }
    else if (b <= 13) { int t = b - 10; src = wp.p[7] + t * 16384;  K = 128; N = 128; Np = 128; Kp = 128; off = 61440 + t * 32768; }
    else if (b <= 17) { int t = b - 14; src = wp.p[8] + t * 4096;   K = 128; N = 32;  Np = 32;  Kp = 128; off = 77824 + t * 32768; }
    else if (b <= 21) { int t = b - 18; src = wp.p[9] + t * 8192;   K = 64;  N = 128; Np = 128; Kp = 64;  off = 180224 + t * 28672; }
    else if (b <= 25) { int t = b - 22; src = wp.p[10] + t * 16384; K = 128; N = 128; Np = 128; Kp = 128; off = 188416 + t * 28672; }
    else if (b <= 29) { int t = b - 26; src = wp.p[11] + t * 4096;  K = 128; N = 32;  Np = 32;  Kp = 128; off = 204800 + t * 28672; }
    else if (b == 30) { src = wp.p[12]; K = 32;  N = 128; Np = 128; Kp = 32;  off = 294912; }
    else if (b == 31) { src = wp.p[13]; K = 128; N = 128; Np = 128; Kp = 128; off = 299008; }
    else              { src = wp.p[14]; K = 128; N = 1;   Np = 16;  Kp = 128; off = 315392; }
    int total = Np * Kp;
    for (int i = threadIdx.x; i < total; i += 256) {
        int n = i / Kp, k = i - n * Kp;
        float v = (k < K && n < N) ? src[k * N + n] : 0.f;
        ws[off + i] = (_Float16)v;
    }
}

// ---------------- CSR build: histogram -> scan -> scatter (u32 atomics only) -----
__global__ void k_zero(unsigned* __restrict__ p, int n) {
    int i = blockIdx.x * 256 + threadIdx.x;
    if (i < n) p[i] = 0u;
}
__global__ void k_hist(const int* __restrict__ gi, unsigned* __restrict__ cnt) {
    int e = blockIdx.x * 256 + threadIdx.x;
    if (e < 512000) atomicAdd(&cnt[gi[2 * e + 1]], 1u);
}
// one block, 1024 threads: exclusive scan of cnt[0..32000) via Kogge-Stone.
__global__ __launch_bounds__(1024) void k_scan(
    const unsigned* __restrict__ cnt, unsigned* __restrict__ rowptr,
    unsigned* __restrict__ cursor) {
    __shared__ unsigned s[1024];
    int t = threadIdx.x;
    unsigned loc[32];
    unsigned sum = 0;
#pragma unroll
    for (int i = 0; i < 32; ++i) {
        int idx = t * 32 + i;
        unsigned v = (idx < 32000) ? cnt[idx] : 0u;
        loc[i] = v; sum += v;
    }
    s[t] = sum;
    __syncthreads();
#pragma unroll
    for (int d = 1; d < 1024; d <<= 1) {
        unsigned x = (t >= d) ? s[t - d] : 0u;
        __syncthreads();
        s[t] += x;
        __syncthreads();
    }
    if (t == 1023) rowptr[32000] = s[1023];
    unsigned off = (t == 0) ? 0u : s[t - 1];
#pragma unroll
    for (int i = 0; i < 32; ++i) {
        int idx = t * 32 + i;
        if (idx < 32000) { rowptr[idx] = off; cursor[idx] = off; off += loc[i]; }
    }
}
__global__ void k_scatter(const int* __restrict__ gi, unsigned* __restrict__ cursor,
                          unsigned* __restrict__ iperm, int2* __restrict__ sr) {
    int e = blockIdx.x * 256 + threadIdx.x;
    if (e < 512000) {
        int s = gi[2 * e], r = gi[2 * e + 1];
        unsigned pos = atomicAdd(&cursor[r], 1u);
        iperm[pos] = (unsigned)e;
        sr[pos] = make_int2(s, r);
    }
}

// ---------------- encoder: fp32 [M][3] -> MLP -> f16 out rows (64-row tiles) -----
__global__ __launch_bounds__(256, 3) void k_enc(
    const float* __restrict__ in, _Float16* __restrict__ out,
    const _Float16* __restrict__ w0t, const _Float16* __restrict__ w1t,
    const _Float16* __restrict__ w2t, int NT, const unsigned* __restrict__ iperm) {
    __shared__ __align__(16) _Float16 Xp[64 * 40];
    __shared__ __align__(16) _Float16 H0[64 * 136];
    __shared__ __align__(16) _Float16 H1[64 * 136];
    const int tid = threadIdx.x, w = tid >> 6, lane = tid & 63;
    const int q = lane >> 4, l16 = lane & 15;
    f16x8 w0f[1][2], w1f[4][2], w2f[4];
    load_wf2<1>(w0t, 32, w * 32, l16, q, w0f);
    load_wf2<4>(w1t, 128, w * 32, l16, q, w1f);
    {
        int n2 = (w & 1) * 16 + l16;
#pragma unroll
        for (int ks = 0; ks < 4; ++ks)
            w2f[ks] = *(const f16x8*)(w2t + n2 * 128 + ks * 32 + q * 8);
    }
    for (int c = tid; c < 2560; c += 256) Xp[c] = (_Float16)0.f;
    BAR();

    const int g = gridDim.x;
    const int dr = tid / 3, dc = tid - dr * 3;  // valid when tid<192
    const int orow = (w >> 1) * 16 + l16, ocol = (w & 1) * 16 + q * 4;
    int t = blockIdx.x;

    while (true) {
        if (tid < 192) {
            unsigned e = iperm ? iperm[t * 64 + dr] : (unsigned)(t * 64 + dr);
            Xp[dr * 40 + dc] = (_Float16)in[e * 3 + dc];
        }
        BAR();
        l01<1, 4>(w0f, w1f, Xp, 40, H0, H1, l16, w, q);
#pragma unroll
        for (int gg = 0; gg < 2; ++gg) {
            f32x4 o = l2g(w2f, H1, l16, w, q, gg);
            f16x4 ov;
#pragma unroll
            for (int i = 0; i < 4; ++i) ov[i] = (_Float16)o[i];
            *(f16x4*)(out + (t * 64 + gg * 32 + orow) * 32 + ocol) = ov;
        }
        t += g;
        if (t >= NT) break;
    }
}

// ---------------- edge update: [edge|node_s|node_r](96) -> MLP -> +res -----------
// R13-proven: 64-row tiles, register staging (gather -> ds_write), sr prefetched
// one tile ahead, residual's old value read from LDS after the staging barrier.
__global__ __launch_bounds__(256, 3) void k_edge(
    const _Float16* __restrict__ node, _Float16* __restrict__ edgeP,
    const int2* __restrict__ sr,
    const _Float16* __restrict__ w0t, const _Float16* __restrict__ w1t,
    const _Float16* __restrict__ w2t) {
    __shared__ __align__(16) _Float16 Xe[64 * 104];
    __shared__ __align__(16) _Float16 H0[64 * 136];
    __shared__ __align__(16) _Float16 H1[64 * 136];
    const int tid = threadIdx.x, w = tid >> 6, lane = tid & 63;
    const int q = lane >> 4, l16 = lane & 15;
    f16x8 w0f[3][2], w1f[4][2], w2f[4];
    load_wf2<3>(w0t, 96, w * 32, l16, q, w0f);
    load_wf2<4>(w1t, 128, w * 32, l16, q, w1f);
    {
        int n2 = (w & 1) * 16 + l16;
#pragma unroll
        for (int ks = 0; ks < 4; ++ks)
            w2f[ks] = *(const f16x8*)(w2t + n2 * 128 + ks * 32 + q * 8);
    }
    int cr[3], cs[3];
#pragma unroll
    for (int j = 0; j < 3; ++j) {
        int c = tid + 256 * j;
        cr[j] = c / 12; cs[j] = c - cr[j] * 12;
    }
    const int orow = (w >> 1) * 16 + l16, ocol = (w & 1) * 16 + q * 4;

    const int NT = 8000, g = gridDim.x;
    int t = blockIdx.x;
    int2 srv[3];
#pragma unroll
    for (int j = 0; j < 3; ++j) srv[j] = sr[t * 64 + cr[j]];

    while (true) {
        int tn = t + g; if (tn >= NT) tn = t;
        // stage tile t (loads issue; Xe write waits on them via vmcnt)
        int4 v[3];
#pragma unroll
        for (int j = 0; j < 3; ++j) {
            int s = cs[j];
            const _Float16* src = (s < 4) ? edgeP + (t * 64 + cr[j]) * 32 + s * 8
                               : (s < 8) ? node + srv[j].x * 32 + (s - 4) * 8
                                         : node + srv[j].y * 32 + (s - 8) * 8;
            v[j] = *(const int4*)src;
        }
        int2 srn[3];
#pragma unroll
        for (int j = 0; j < 3; ++j) srn[j] = sr[tn * 64 + cr[j]];
#pragma unroll
        for (int j = 0; j < 3; ++j)
            *(int4*)(Xe + cr[j] * 104 + cs[j] * 8) = v[j];
        BAR();
        // old edge latent from LDS (cols 0..31 of the staged tile)
        f16x4 oldv[2];
#pragma unroll
        for (int gg = 0; gg < 2; ++gg)
            oldv[gg] = *(const f16x4*)(Xe + (gg * 32 + orow) * 104 + ocol);

        l01<3, 4>(w0f, w1f, Xe, 104, H0, H1, l16, w, q);
#pragma unroll
        for (int gg = 0; gg < 2; ++gg) {
            f32x4 o = l2g(w2f, H1, l16, w, q, gg);
            f16x4 nv;
#pragma unroll
            for (int i = 0; i < 4; ++i) nv[i] = (_Float16)(o[i] + (float)oldv[gg][i]);
            *(f16x4*)(edgeP + (t * 64 + gg * 32 + orow) * 32 + ocol) = nv;
        }

        if (tn == t) break;
        t = tn;
#pragma unroll
        for (int j = 0; j < 3; ++j) srv[j] = srn[j];
    }
}

// ---------------- node update: [node|csr_sum(edgeP)](64) -> MLP -> +res ----------
// Proven 32-row data path; 2-iteration grid-stride loop (verified in R15's pass)
// halves per-block fixed weight-load cost.
__global__ __launch_bounds__(256, 3) void k_node(
    _Float16* __restrict__ node, const _Float16* __restrict__ edgeP,
    const unsigned* __restrict__ rowptr,
    const _Float16* __restrict__ w0t, const _Float16* __restrict__ w1t,
    const _Float16* __restrict__ w2t) {
    __shared__ __align__(16) _Float16 Xn[32 * 72];
    __shared__ __align__(16) _Float16 H0[32 * 136];
    __shared__ __align__(16) _Float16 H1[32 * 136];
    const int tid = threadIdx.x, w = tid >> 6, lane = tid & 63;
    const int q = lane >> 4, l16 = lane & 15;
    f16x8 w0f[2][2], w1f[4][2], w2f[4];
    load_wf2<2>(w0t, 64, w * 32, l16, q, w0f);
    load_wf2<4>(w1t, 128, w * 32, l16, q, w1f);
    {
        int n2 = (w & 1) * 16 + l16;
#pragma unroll
        for (int ks = 0; ks < 4; ++ks)
            w2f[ks] = *(const f16x8*)(w2t + n2 * 128 + ks * 32 + q * 8);
    }
    const int orow = (w >> 1) * 16 + l16, ocol = (w & 1) * 16 + q * 4;
    const int g = gridDim.x;
    for (int t = blockIdx.x; t < 1000; t += g) {
        // 8 chunks/row (16 B each): cs<4 node copy, cs>=4 segment-sum of edgeP chunk
        {
            int cr = tid >> 3, cs = tid & 7;
            int r = t * 32 + cr;
            if (cs < 4) {
                *(int4*)(Xn + cr * 72 + cs * 8) = *(const int4*)(node + r * 32 + cs * 8);
            } else {
                unsigned b = rowptr[r], e = rowptr[r + 1];
                const _Float16* base = edgeP + (cs - 4) * 8;
                float a0[8], a1[8];
#pragma unroll
                for (int i = 0; i < 8; ++i) { a0[i] = 0.f; a1[i] = 0.f; }
                unsigned p = b;
                for (; p + 2 <= e; p += 2) {
                    f16x8 x0 = *(const f16x8*)(base + (p + 0) * 32);
                    f16x8 x1 = *(const f16x8*)(base + (p + 1) * 32);
#pragma unroll
                    for (int i = 0; i < 8; ++i) { a0[i] += (float)x0[i]; a1[i] += (float)x1[i]; }
                }
                if (p < e) {
                    f16x8 x0 = *(const f16x8*)(base + p * 32);
#pragma unroll
                    for (int i = 0; i < 8; ++i) a0[i] += (float)x0[i];
                }
                f16x8 h;
#pragma unroll
                for (int i = 0; i < 8; ++i) h[i] = (_Float16)(a0[i] + a1[i]);
                *(f16x8*)(Xn + cr * 72 + cs * 8) = h;
            }
        }
        BAR();
        f16x4 oldv = *(const f16x4*)(Xn + orow * 72 + ocol);
        l01<2, 2>(w0f, w1f, Xn, 72, H0, H1, l16, w, q);
        f32x4 o = l2g(w2f, H1, l16, w, q, 0);
        f16x4 nv;
#pragma unroll
        for (int i = 0; i < 4; ++i) nv[i] = (_Float16)(o[i] + (float)oldv[i]);
        *(f16x4*)(node + (t * 32 + orow) * 32 + ocol) = nv;
    }
}

// ---------------- decoder: node(32) -> MLP(32->128->128->1) -> fp32 out ----------
__global__ __launch_bounds__(256, 3) void k_dec(
    const _Float16* __restrict__ node,
    const _Float16* __restrict__ w0t, const _Float16* __restrict__ w1t,
    const _Float16* __restrict__ w2t, float* __restrict__ out) {
    __shared__ __align__(16) _Float16 Xd[64 * 40];
    __shared__ __align__(16) _Float16 H0[64 * 136];
    __shared__ __align__(16) _Float16 H1[64 * 136];
    const int tid = threadIdx.x, w = tid >> 6, lane = tid & 63;
    const int q = lane >> 4, l16 = lane & 15;
    f16x8 w0f[1][2], w1f[4][2], w2f[4];
    load_wf2<1>(w0t, 32, w * 32, l16, q, w0f);
    load_wf2<4>(w1t, 128, w * 32, l16, q, w1f);
    {
        int n2 = l16;  // padded W2^T is [16][128]; all waves load tile 0
#pragma unroll
        for (int ks = 0; ks < 4; ++ks)
            w2f[ks] = *(const f16x8*)(w2t + n2 * 128 + ks * 32 + q * 8);
    }
    const int t = blockIdx.x;
    {
        int cr = tid >> 2, cs = tid & 3;
        *(int4*)(Xd + cr * 40 + cs * 8) = *(const int4*)(node + (t * 64 + cr) * 32 + cs * 8);
    }
    BAR();
    l01<1, 4>(w0f, w1f, Xd, 40, H0, H1, l16, w, q);
#pragma unroll
    for (int gg = 0; gg < 2; ++gg) {
        f32x4 o = l2g(w2f, H1, l16, w, q, gg);
        // only col 0 is real: waves with (w&1)==0, lanes q==0, reg 0
        if ((w & 1) == 0 && q == 0) out[t * 64 + gg * 32 + (w >> 1) * 16 + l16] = o[0];
    }
}

extern "C" void kernel_launch(void* const* d_in, const int* in_sizes, int n_in,
                              void* d_out, int out_size, void* d_ws, size_t ws_size,
                              hipStream_t stream) {
    const float* input_node = (const float*)d_in[0];
    const float* input_edge = (const float*)d_in[1];
    const int* gi = (const int*)d_in[2];

    _Float16* ws = (_Float16*)d_ws;
    // ws layout (bytes):
    //   weights f16:         [0,          634,880)
    //   node  f16 32000x32:  [655,360,    2,703,360)
    //   edgeP f16 512000x32: [2,703,360,  35,471,360)   (receiver-sorted rows)
    //   rowptr u32[32001]:   [35,471,360, 35,599,364)
    //   cursor u32[32000]:   [35,599,616, 35,727,616)
    //   iperm  u32[512000]:  [35,727,616, 37,775,616)
    //   sr   int2[512000]:   [37,775,616, 41,871,616)
    _Float16* node = (_Float16*)((char*)d_ws + 655360);
    _Float16* edgeP = (_Float16*)((char*)d_ws + 2703360);
    unsigned* rowptr = (unsigned*)((char*)d_ws + 35471360);
    unsigned* cursor = (unsigned*)((char*)d_ws + 35599616);
    unsigned* iperm = (unsigned*)((char*)d_ws + 35727616);
    int2* sr = (int2*)((char*)d_ws + 37775616);

    WPtrs wp;
    for (int i = 0; i < 15; ++i) wp.p[i] = (const float*)d_in[3 + i];

    k_prep<<<33, 256, 0, stream>>>(wp, ws);

    // CSR build (u32 atomics only)
    k_zero<<<125, 256, 0, stream>>>(cursor, 32000);
    k_hist<<<2000, 256, 0, stream>>>(gi, cursor);
    k_scan<<<1, 1024, 0, stream>>>(cursor, rowptr, cursor);
    k_scatter<<<2000, 256, 0, stream>>>(gi, cursor, iperm, sr);

    k_enc<<<500, 256, 0, stream>>>(input_node, node, ws + 0, ws + 4096, ws + 20480,
                                   500, nullptr);
    k_enc<<<768, 256, 0, stream>>>(input_edge, edgeP, ws + 24576, ws + 28672,
                                   ws + 45056, 8000, iperm);

    for (int t = 0; t < 4; ++t) {
        k_edge<<<768, 256, 0, stream>>>(node, edgeP, sr,
                                        ws + 49152 + t * 32768,
                                        ws + 61440 + t * 32768,
                                        ws + 77824 + t * 32768);
        k_node<<<500, 256, 0, stream>>>(node, edgeP, rowptr,
                                        ws + 180224 + t * 28672,
                                        ws + 188416 + t * 28672,
                                        ws + 204800 + t * 28672);
    }
    k_dec<<<500, 256, 0, stream>>>(node, ws + 294912, ws + 299008, ws + 315392,
                                   (float*)d_out);
}

// Round 17
// 507.760 us; speedup vs baseline: 1.0523x; 1.0026x over previous
//
#include <hip/hip_runtime.h>

typedef __attribute__((ext_vector_type(8))) _Float16 f16x8;
typedef __attribute__((ext_vector_type(4))) _Float16 f16x4;
typedef __attribute__((ext_vector_type(4))) float f32x4;

#define DI __device__ __forceinline__
// Raw barrier: LDS-drain only (lgkmcnt). Avoids the compiler's vmcnt(0) drain.
#define BAR() asm volatile("s_waitcnt lgkmcnt(0)\n\ts_barrier" ::: "memory")

DI f32x4 mfma16(f16x8 a, f16x8 b, f32x4 c) {
    return __builtin_amdgcn_mfma_f32_16x16x32_f16(a, b, c, 0, 0, 0);
}

// Wave-mapping: wave w owns features [w*32, w*32+32) for layers 0/1 (2 n-tiles,
// weight frags reused across all MH m-groups of 16 rows). Layer 2: wave w computes
// rows (w>>1)*16 (+32*g) and cols (w&1)*16 of the MHx16 x 32 output.
// PROVEN (R13/R16, ~504-509 us): lb(256,3), register staging in k_edge, sr one
// tile ahead. Failed levers (do not retry): lb(256,4) [evicts weights], explicit
// data pipeline [spills], glds async staging [R14/R15 slower], 64-row MH=4 k_node
// [R12 diverges].

template <int NK>
DI void load_wf2(const _Float16* __restrict__ wt, int Kp, int nbase, int l16, int q,
                 f16x8 f[NK][2]) {
#pragma unroll
    for (int nt = 0; nt < 2; ++nt) {
        int n = nbase + nt * 16 + l16;
#pragma unroll
        for (int ks = 0; ks < NK; ++ks)
            f[ks][nt] = *(const f16x8*)(wt + n * Kp + ks * 32 + q * 8);
    }
}

// Layers 0/1 over MH 16-row groups: D' = W^T X^T; relu'd f16 to H (stride 136).
template <int NK0, int MH>
DI void l01(const f16x8 (*w0f)[2], const f16x8 (*w1f)[2],
            const _Float16* __restrict__ X, int xstride,
            _Float16* __restrict__ H0, _Float16* __restrict__ H1,
            int l16, int w, int q) {
    const f32x4 zero = {0.f, 0.f, 0.f, 0.f};
    f32x4 acc[2][MH];
#pragma unroll
    for (int nt = 0; nt < 2; ++nt)
#pragma unroll
        for (int mt = 0; mt < MH; ++mt) acc[nt][mt] = zero;
#pragma unroll
    for (int ks = 0; ks < NK0; ++ks) {
        f16x8 x[MH];
#pragma unroll
        for (int mt = 0; mt < MH; ++mt)
            x[mt] = *(const f16x8*)(X + (mt * 16 + l16) * xstride + ks * 32 + q * 8);
#pragma unroll
        for (int nt = 0; nt < 2; ++nt)
#pragma unroll
            for (int mt = 0; mt < MH; ++mt)
                acc[nt][mt] = mfma16(w0f[ks][nt], x[mt], acc[nt][mt]);
    }
#pragma unroll
    for (int mt = 0; mt < MH; ++mt)
#pragma unroll
        for (int nt = 0; nt < 2; ++nt) {
            f16x4 h;
#pragma unroll
            for (int i = 0; i < 4; ++i) h[i] = (_Float16)fmaxf(acc[nt][mt][i], 0.f);
            *(f16x4*)(H0 + (mt * 16 + l16) * 136 + w * 32 + nt * 16 + q * 4) = h;
        }
    BAR();
    f32x4 a1[2][MH];
#pragma unroll
    for (int nt = 0; nt < 2; ++nt)
#pragma unroll
        for (int mt = 0; mt < MH; ++mt) a1[nt][mt] = zero;
#pragma unroll
    for (int ks = 0; ks < 4; ++ks) {
        f16x8 x[MH];
#pragma unroll
        for (int mt = 0; mt < MH; ++mt)
            x[mt] = *(const f16x8*)(H0 + (mt * 16 + l16) * 136 + ks * 32 + q * 8);
#pragma unroll
        for (int nt = 0; nt < 2; ++nt)
#pragma unroll
            for (int mt = 0; mt < MH; ++mt)
                a1[nt][mt] = mfma16(w1f[ks][nt], x[mt], a1[nt][mt]);
    }
#pragma unroll
    for (int mt = 0; mt < MH; ++mt)
#pragma unroll
        for (int nt = 0; nt < 2; ++nt) {
            f16x4 h;
#pragma unroll
            for (int i = 0; i < 4; ++i) h[i] = (_Float16)fmaxf(a1[nt][mt][i], 0.f);
            *(f16x4*)(H1 + (mt * 16 + l16) * 136 + w * 32 + nt * 16 + q * 4) = h;
        }
    BAR();
}

// Layer 2, row group g: rows (w>>1)*16 + l16 + 32*g, cols (w&1)*16 + q*4 + i.
DI f32x4 l2g(const f16x8* w2f, const _Float16* __restrict__ H1, int l16, int w,
             int q, int g) {
    int m = (w >> 1) * 16 + l16 + 32 * g;
    f32x4 acc = {0.f, 0.f, 0.f, 0.f};
#pragma unroll
    for (int ks = 0; ks < 4; ++ks) {
        f16x8 x = *(const f16x8*)(H1 + m * 136 + ks * 32 + q * 8);
        acc = mfma16(w2f[ks], x, acc);
    }
    return acc;
}

// ---------------- weight prep: fp32 [K][N] -> f16 W^T [Np][Kp] (zero padded) ----
// Blocks 33..157 additionally zero the CSR cursor (fused former k_zero).
struct WPtrs { const float* p[15]; };

__global__ void k_prep(WPtrs wp, _Float16* __restrict__ ws,
                       unsigned* __restrict__ cursor) {
    int b = blockIdx.x;
    if (b >= 33) {
        int i = (b - 33) * 256 + threadIdx.x;
        if (i < 32000) cursor[i] = 0u;
        return;
    }
    const float* src; int K, N, Np, Kp, off;
    if (b == 0)       { src = wp.p[0];  K = 3;   N = 128; Np = 128; Kp = 32;  off = 0; }
    else if (b == 1)  { src = wp.p[1];  K = 128; N = 128; Np = 128; Kp = 128; off = 4096; }
    else if (b == 2)  { src = wp.p[2];  K = 128; N = 32;  Np = 32;  Kp = 128; off = 20480; }
    else if (b == 3)  { src = wp.p[3];  K = 3;   N = 128; Np = 128; Kp = 32;  off = 24576; }
    else if (b == 4)  { src = wp.p[4];  K = 128; N = 128; Np = 128; Kp = 128; off = 28672; }
    else if (b == 5)  { src = wp.p[5];  K = 128; N = 32;  Np = 32;  Kp = 128; off = 45056; }
    else if (b <= 9)  { int t = b - 6;  src = wp.p[6] + t * 12288;  K = 96;  N = 128; Np = 128; Kp = 96;  off = 49152 + t * 32768; }
    else if (b <= 13) { int t = b - 10; src = wp.p[7] + t * 16384;  K = 128; N = 128; Np = 128; Kp = 128; off = 61440 + t * 32768; }
    else if (b <= 17) { int t = b - 14; src = wp.p[8] + t * 4096;   K = 128; N = 32;  Np = 32;  Kp = 128; off = 77824 + t * 32768; }
    else if (b <= 21) { int t = b - 18; src = wp.p[9] + t * 8192;   K = 64;  N = 128; Np = 128; Kp = 64;  off = 180224 + t * 28672; }
    else if (b <= 25) { int t = b - 22; src = wp.p[10] + t * 16384; K = 128; N = 128; Np = 128; Kp = 128; off = 188416 + t * 28672; }
    else if (b <= 29) { int t = b - 26; src = wp.p[11] + t * 4096;  K = 128; N = 32;  Np = 32;  Kp = 128; off = 204800 + t * 28672; }
    else if (b == 30) { src = wp.p[12]; K = 32;  N = 128; Np = 128; Kp = 32;  off = 294912; }
    else if (b == 31) { src = wp.p[13]; K = 128; N = 128; Np = 128; Kp = 128; off = 299008; }
    else              { src = wp.p[14]; K = 128; N = 1;   Np = 16;  Kp = 128; off = 315392; }
    int total = Np * Kp;
    for (int i = threadIdx.x; i < total; i += 256) {
        int n = i / Kp, k = i - n * Kp;
        float v = (k < K && n < N) ? src[k * N + n] : 0.f;
        ws[off + i] = (_Float16)v;
    }
}

// ---------------- CSR build: histogram -> scan -> scatter (u32 atomics only) -----
__global__ void k_hist(const int* __restrict__ gi, unsigned* __restrict__ cnt) {
    int e = blockIdx.x * 256 + threadIdx.x;
    if (e < 512000) atomicAdd(&cnt[gi[2 * e + 1]], 1u);
}
// one block, 1024 threads: exclusive scan of cnt[0..32000) via Kogge-Stone.
__global__ __launch_bounds__(1024) void k_scan(
    const unsigned* __restrict__ cnt, unsigned* __restrict__ rowptr,
    unsigned* __restrict__ cursor) {
    __shared__ unsigned s[1024];
    int t = threadIdx.x;
    unsigned loc[32];
    unsigned sum = 0;
#pragma unroll
    for (int i = 0; i < 32; ++i) {
        int idx = t * 32 + i;
        unsigned v = (idx < 32000) ? cnt[idx] : 0u;
        loc[i] = v; sum += v;
    }
    s[t] = sum;
    __syncthreads();
#pragma unroll
    for (int d = 1; d < 1024; d <<= 1) {
        unsigned x = (t >= d) ? s[t - d] : 0u;
        __syncthreads();
        s[t] += x;
        __syncthreads();
    }
    if (t == 1023) rowptr[32000] = s[1023];
    unsigned off = (t == 0) ? 0u : s[t - 1];
#pragma unroll
    for (int i = 0; i < 32; ++i) {
        int idx = t * 32 + i;
        if (idx < 32000) { rowptr[idx] = off; cursor[idx] = off; off += loc[i]; }
    }
}
// sr packed as u32: sender | (receiver<<16); both indices < 32000 < 2^16.
__global__ void k_scatter(const int* __restrict__ gi, unsigned* __restrict__ cursor,
                          unsigned* __restrict__ iperm, unsigned* __restrict__ sr) {
    int e = blockIdx.x * 256 + threadIdx.x;
    if (e < 512000) {
        int s = gi[2 * e], r = gi[2 * e + 1];
        unsigned pos = atomicAdd(&cursor[r], 1u);
        iperm[pos] = (unsigned)e;
        sr[pos] = (unsigned)s | ((unsigned)r << 16);
    }
}

// ---------------- fused encoder: nodes (blocks <500) + edges (blocks >=500) -----
// fp32 [M][3] -> MLP(32p->128->128->32) -> f16 out rows (64-row tiles).
__global__ __launch_bounds__(256, 3) void k_enc2(
    const float* __restrict__ in_n, _Float16* __restrict__ out_n,
    const float* __restrict__ in_e, _Float16* __restrict__ out_e,
    const unsigned* __restrict__ iperm,
    const _Float16* __restrict__ nw0, const _Float16* __restrict__ nw1,
    const _Float16* __restrict__ nw2,
    const _Float16* __restrict__ ew0, const _Float16* __restrict__ ew1,
    const _Float16* __restrict__ ew2) {
    __shared__ __align__(16) _Float16 Xp[64 * 40];
    __shared__ __align__(16) _Float16 H0[64 * 136];
    __shared__ __align__(16) _Float16 H1[64 * 136];
    const bool isNode = blockIdx.x < 500;
    const float* in = isNode ? in_n : in_e;
    _Float16* out = isNode ? out_n : out_e;
    const _Float16* w0t = isNode ? nw0 : ew0;
    const _Float16* w1t = isNode ? nw1 : ew1;
    const _Float16* w2t = isNode ? nw2 : ew2;
    const unsigned* ip = isNode ? nullptr : iperm;
    const int NT = isNode ? 500 : 8000;
    const int g = isNode ? 500 : 768;
    int t = isNode ? blockIdx.x : blockIdx.x - 500;

    const int tid = threadIdx.x, w = tid >> 6, lane = tid & 63;
    const int q = lane >> 4, l16 = lane & 15;
    f16x8 w0f[1][2], w1f[4][2], w2f[4];
    load_wf2<1>(w0t, 32, w * 32, l16, q, w0f);
    load_wf2<4>(w1t, 128, w * 32, l16, q, w1f);
    {
        int n2 = (w & 1) * 16 + l16;
#pragma unroll
        for (int ks = 0; ks < 4; ++ks)
            w2f[ks] = *(const f16x8*)(w2t + n2 * 128 + ks * 32 + q * 8);
    }
    for (int c = tid; c < 2560; c += 256) Xp[c] = (_Float16)0.f;
    BAR();

    const int dr = tid / 3, dc = tid - dr * 3;  // valid when tid<192
    const int orow = (w >> 1) * 16 + l16, ocol = (w & 1) * 16 + q * 4;

    while (true) {
        if (tid < 192) {
            unsigned e = ip ? ip[t * 64 + dr] : (unsigned)(t * 64 + dr);
            Xp[dr * 40 + dc] = (_Float16)in[e * 3 + dc];
        }
        BAR();
        l01<1, 4>(w0f, w1f, Xp, 40, H0, H1, l16, w, q);
#pragma unroll
        for (int gg = 0; gg < 2; ++gg) {
            f32x4 o = l2g(w2f, H1, l16, w, q, gg);
            f16x4 ov;
#pragma unroll
            for (int i = 0; i < 4; ++i) ov[i] = (_Float16)o[i];
            *(f16x4*)(out + (t * 64 + gg * 32 + orow) * 32 + ocol) = ov;
        }
        t += g;
        if (t >= NT) break;
    }
}

// ---------------- edge update: [edge|node_s|node_r](96) -> MLP -> +res -----------
// R13-proven: 64-row tiles, register staging (gather -> ds_write), packed-u32 sr
// prefetched one tile ahead, residual's old value read from LDS post-barrier.
__global__ __launch_bounds__(256, 3) void k_edge(
    const _Float16* __restrict__ node, _Float16* __restrict__ edgeP,
    const unsigned* __restrict__ sr,
    const _Float16* __restrict__ w0t, const _Float16* __restrict__ w1t,
    const _Float16* __restrict__ w2t) {
    __shared__ __align__(16) _Float16 Xe[64 * 104];
    __shared__ __align__(16) _Float16 H0[64 * 136];
    __shared__ __align__(16) _Float16 H1[64 * 136];
    const int tid = threadIdx.x, w = tid >> 6, lane = tid & 63;
    const int q = lane >> 4, l16 = lane & 15;
    f16x8 w0f[3][2], w1f[4][2], w2f[4];
    load_wf2<3>(w0t, 96, w * 32, l16, q, w0f);
    load_wf2<4>(w1t, 128, w * 32, l16, q, w1f);
    {
        int n2 = (w & 1) * 16 + l16;
#pragma unroll
        for (int ks = 0; ks < 4; ++ks)
            w2f[ks] = *(const f16x8*)(w2t + n2 * 128 + ks * 32 + q * 8);
    }
    int cr[3], cs[3];
#pragma unroll
    for (int j = 0; j < 3; ++j) {
        int c = tid + 256 * j;
        cr[j] = c / 12; cs[j] = c - cr[j] * 12;
    }
    const int orow = (w >> 1) * 16 + l16, ocol = (w & 1) * 16 + q * 4;

    const int NT = 8000, g = gridDim.x;
    int t = blockIdx.x;
    unsigned srv[3];
#pragma unroll
    for (int j = 0; j < 3; ++j) srv[j] = sr[t * 64 + cr[j]];

    while (true) {
        int tn = t + g; if (tn >= NT) tn = t;
        // stage tile t (loads issue; Xe write waits on them via vmcnt)
        int4 v[3];
#pragma unroll
        for (int j = 0; j < 3; ++j) {
            int s = cs[j];
            const _Float16* src = (s < 4) ? edgeP + (t * 64 + cr[j]) * 32 + s * 8
                               : (s < 8) ? node + (srv[j] & 0xffffu) * 32 + (s - 4) * 8
                                         : node + (srv[j] >> 16) * 32 + (s - 8) * 8;
            v[j] = *(const int4*)src;
        }
        unsigned srn[3];
#pragma unroll
        for (int j = 0; j < 3; ++j) srn[j] = sr[tn * 64 + cr[j]];
#pragma unroll
        for (int j = 0; j < 3; ++j)
            *(int4*)(Xe + cr[j] * 104 + cs[j] * 8) = v[j];
        BAR();
        // old edge latent from LDS (cols 0..31 of the staged tile)
        f16x4 oldv[2];
#pragma unroll
        for (int gg = 0; gg < 2; ++gg)
            oldv[gg] = *(const f16x4*)(Xe + (gg * 32 + orow) * 104 + ocol);

        l01<3, 4>(w0f, w1f, Xe, 104, H0, H1, l16, w, q);
#pragma unroll
        for (int gg = 0; gg < 2; ++gg) {
            f32x4 o = l2g(w2f, H1, l16, w, q, gg);
            f16x4 nv;
#pragma unroll
            for (int i = 0; i < 4; ++i) nv[i] = (_Float16)(o[i] + (float)oldv[gg][i]);
            *(f16x4*)(edgeP + (t * 64 + gg * 32 + orow) * 32 + ocol) = nv;
        }

        if (tn == t) break;
        t = tn;
#pragma unroll
        for (int j = 0; j < 3; ++j) srv[j] = srn[j];
    }
}

// ---------------- node update: [node|csr_sum(edgeP)](64) -> MLP -> +res ----------
// Proven 32-row data path; 2-iteration grid-stride loop (verified R15/R16).
__global__ __launch_bounds__(256, 3) void k_node(
    _Float16* __restrict__ node, const _Float16* __restrict__ edgeP,
    const unsigned* __restrict__ rowptr,
    const _Float16* __restrict__ w0t, const _Float16* __restrict__ w1t,
    const _Float16* __restrict__ w2t) {
    __shared__ __align__(16) _Float16 Xn[32 * 72];
    __shared__ __align__(16) _Float16 H0[32 * 136];
    __shared__ __align__(16) _Float16 H1[32 * 136];
    const int tid = threadIdx.x, w = tid >> 6, lane = tid & 63;
    const int q = lane >> 4, l16 = lane & 15;
    f16x8 w0f[2][2], w1f[4][2], w2f[4];
    load_wf2<2>(w0t, 64, w * 32, l16, q, w0f);
    load_wf2<4>(w1t, 128, w * 32, l16, q, w1f);
    {
        int n2 = (w & 1) * 16 + l16;
#pragma unroll
        for (int ks = 0; ks < 4; ++ks)
            w2f[ks] = *(const f16x8*)(w2t + n2 * 128 + ks * 32 + q * 8);
    }
    const int orow = (w >> 1) * 16 + l16, ocol = (w & 1) * 16 + q * 4;
    const int g = gridDim.x;
    for (int t = blockIdx.x; t < 1000; t += g) {
        // 8 chunks/row (16 B each): cs<4 node copy, cs>=4 segment-sum of edgeP chunk
        {
            int cr = tid >> 3, cs = tid & 7;
            int r = t * 32 + cr;
            if (cs < 4) {
                *(int4*)(Xn + cr * 72 + cs * 8) = *(const int4*)(node + r * 32 + cs * 8);
            } else {
                unsigned b = rowptr[r], e = rowptr[r + 1];
                const _Float16* base = edgeP + (cs - 4) * 8;
                float a0[8], a1[8];
#pragma unroll
                for (int i = 0; i < 8; ++i) { a0[i] = 0.f; a1[i] = 0.f; }
                unsigned p = b;
                for (; p + 2 <= e; p += 2) {
                    f16x8 x0 = *(const f16x8*)(base + (p + 0) * 32);
                    f16x8 x1 = *(const f16x8*)(base + (p + 1) * 32);
#pragma unroll
                    for (int i = 0; i < 8; ++i) { a0[i] += (float)x0[i]; a1[i] += (float)x1[i]; }
                }
                if (p < e) {
                    f16x8 x0 = *(const f16x8*)(base + p * 32);
#pragma unroll
                    for (int i = 0; i < 8; ++i) a0[i] += (float)x0[i];
                }
                f16x8 h;
#pragma unroll
                for (int i = 0; i < 8; ++i) h[i] = (_Float16)(a0[i] + a1[i]);
                *(f16x8*)(Xn + cr * 72 + cs * 8) = h;
            }
        }
        BAR();
        f16x4 oldv = *(const f16x4*)(Xn + orow * 72 + ocol);
        l01<2, 2>(w0f, w1f, Xn, 72, H0, H1, l16, w, q);
        f32x4 o = l2g(w2f, H1, l16, w, q, 0);
        f16x4 nv;
#pragma unroll
        for (int i = 0; i < 4; ++i) nv[i] = (_Float16)(o[i] + (float)oldv[i]);
        *(f16x4*)(node + (t * 32 + orow) * 32 + ocol) = nv;
    }
}

// ---------------- decoder: node(32) -> MLP(32->128->128->1) -> fp32 out ----------
__global__ __launch_bounds__(256, 3) void k_dec(
    const _Float16* __restrict__ node,
    const _Float16* __restrict__ w0t, const _Float16* __restrict__ w1t,
    const _Float16* __restrict__ w2t, float* __restrict__ out) {
    __shared__ __align__(16) _Float16 Xd[64 * 40];
    __shared__ __align__(16) _Float16 H0[64 * 136];
    __shared__ __align__(16) _Float16 H1[64 * 136];
    const int tid = threadIdx.x, w = tid >> 6, lane = tid & 63;
    const int q = lane >> 4, l16 = lane & 15;
    f16x8 w0f[1][2], w1f[4][2], w2f[4];
    load_wf2<1>(w0t, 32, w * 32, l16, q, w0f);
    load_wf2<4>(w1t, 128, w * 32, l16, q, w1f);
    {
        int n2 = l16;  // padded W2^T is [16][128]; all waves load tile 0
#pragma unroll
        for (int ks = 0; ks < 4; ++ks)
            w2f[ks] = *(const f16x8*)(w2t + n2 * 128 + ks * 32 + q * 8);
    }
    const int t = blockIdx.x;
    {
        int cr = tid >> 2, cs = tid & 3;
        *(int4*)(Xd + cr * 40 + cs * 8) = *(const int4*)(node + (t * 64 + cr) * 32 + cs * 8);
    }
    BAR();
    l01<1, 4>(w0f, w1f, Xd, 40, H0, H1, l16, w, q);
#pragma unroll
    for (int gg = 0; gg < 2; ++gg) {
        f32x4 o = l2g(w2f, H1, l16, w, q, gg);
        // only col 0 is real: waves with (w&1)==0, lanes q==0, reg 0
        if ((w & 1) == 0 && q == 0) out[t * 64 + gg * 32 + (w >> 1) * 16 + l16] = o[0];
    }
}

extern "C" void kernel_launch(void* const* d_in, const int* in_sizes, int n_in,
                              void* d_out, int out_size, void* d_ws, size_t ws_size,
                              hipStream_t stream) {
    const float* input_node = (const float*)d_in[0];
    const float* input_edge = (const float*)d_in[1];
    const int* gi = (const int*)d_in[2];

    _Float16* ws = (_Float16*)d_ws;
    // ws layout (bytes):
    //   weights f16:         [0,          634,880)
    //   node  f16 32000x32:  [655,360,    2,703,360)
    //   edgeP f16 512000x32: [2,703,360,  35,471,360)   (receiver-sorted rows)
    //   rowptr u32[32001]:   [35,471,360, 35,599,364)
    //   cursor u32[32000]:   [35,599,616, 35,727,616)
    //   iperm  u32[512000]:  [35,727,616, 37,775,616)
    //   sr     u32[512000]:  [37,775,616, 39,823,616)   (sender | receiver<<16)
    _Float16* node = (_Float16*)((char*)d_ws + 655360);
    _Float16* edgeP = (_Float16*)((char*)d_ws + 2703360);
    unsigned* rowptr = (unsigned*)((char*)d_ws + 35471360);
    unsigned* cursor = (unsigned*)((char*)d_ws + 35599616);
    unsigned* iperm = (unsigned*)((char*)d_ws + 35727616);
    unsigned* sr = (unsigned*)((char*)d_ws + 37775616);

    WPtrs wp;
    for (int i = 0; i < 15; ++i) wp.p[i] = (const float*)d_in[3 + i];

    // weight prep + cursor zero (fused)
    k_prep<<<158, 256, 0, stream>>>(wp, ws, cursor);

    // CSR build (u32 atomics only)
    k_hist<<<2000, 256, 0, stream>>>(gi, cursor);
    k_scan<<<1, 1024, 0, stream>>>(cursor, rowptr, cursor);
    k_scatter<<<2000, 256, 0, stream>>>(gi, cursor, iperm, sr);

    // fused encoder: blocks <500 encode nodes, blocks >=500 encode edges
    k_enc2<<<1268, 256, 0, stream>>>(input_node, node, input_edge, edgeP, iperm,
                                     ws + 0, ws + 4096, ws + 20480,
                                     ws + 24576, ws + 28672, ws + 45056);

    for (int t = 0; t < 4; ++t) {
        k_edge<<<768, 256, 0, stream>>>(node, edgeP, sr,
                                        ws + 49152 + t * 32768,
                                        ws + 61440 + t * 32768,
                                        ws + 77824 + t * 32768);
        k_node<<<500, 256, 0, stream>>>(node, edgeP, rowptr,
                                        ws + 180224 + t * 28672,
                                        ws + 188416 + t * 28672,
                                        ws + 204800 + t * 28672);
    }
    k_dec<<<500, 256, 0, stream>>>(node, ws + 294912, ws + 299008, ws + 315392,
                                   (float*)d_out);
}

// Round 18
// 506.679 us; speedup vs baseline: 1.0545x; 1.0021x over previous
//
#include <hip/hip_runtime.h>

typedef __attribute__((ext_vector_type(8))) _Float16 f16x8;
typedef __attribute__((ext_vector_type(4))) _Float16 f16x4;
typedef __attribute__((ext_vector_type(4))) float f32x4;

#define DI __device__ __forceinline__
// Raw barrier: LDS-drain only (lgkmcnt). Avoids the compiler's vmcnt(0) drain.
#define BAR() asm volatile("s_waitcnt lgkmcnt(0)\n\ts_barrier" ::: "memory")

DI f32x4 mfma16(f16x8 a, f16x8 b, f32x4 c) {
    return __builtin_amdgcn_mfma_f32_16x16x32_f16(a, b, c, 0, 0, 0);
}

// Wave-mapping: wave w owns features [w*32, w*32+32) for layers 0/1 (2 n-tiles,
// weight frags reused across all MH m-groups of 16 rows). Layer 2: wave w computes
// rows (w>>1)*16 (+32*g) and cols (w&1)*16 of the MHx16 x 32 output.
// PROVEN (R13/R16/R17, ~504-509 us): lb(256,3), register staging in k_edge, sr one
// tile ahead. Failed levers (do not retry): lb(256,4) [evicts weights], explicit
// data pipeline [spills], glds async staging [R14/R15 slower], 64-row MH=4 k_node
// [R12 diverges].

template <int NK>
DI void load_wf2(const _Float16* __restrict__ wt, int Kp, int nbase, int l16, int q,
                 f16x8 f[NK][2]) {
#pragma unroll
    for (int nt = 0; nt < 2; ++nt) {
        int n = nbase + nt * 16 + l16;
#pragma unroll
        for (int ks = 0; ks < NK; ++ks)
            f[ks][nt] = *(const f16x8*)(wt + n * Kp + ks * 32 + q * 8);
    }
}

// Layers 0/1 over MH 16-row groups: D' = W^T X^T; relu'd f16 to H (stride 136).
template <int NK0, int MH>
DI void l01(const f16x8 (*w0f)[2], const f16x8 (*w1f)[2],
            const _Float16* __restrict__ X, int xstride,
            _Float16* __restrict__ H0, _Float16* __restrict__ H1,
            int l16, int w, int q) {
    const f32x4 zero = {0.f, 0.f, 0.f, 0.f};
    f32x4 acc[2][MH];
#pragma unroll
    for (int nt = 0; nt < 2; ++nt)
#pragma unroll
        for (int mt = 0; mt < MH; ++mt) acc[nt][mt] = zero;
#pragma unroll
    for (int ks = 0; ks < NK0; ++ks) {
        f16x8 x[MH];
#pragma unroll
        for (int mt = 0; mt < MH; ++mt)
            x[mt] = *(const f16x8*)(X + (mt * 16 + l16) * xstride + ks * 32 + q * 8);
#pragma unroll
        for (int nt = 0; nt < 2; ++nt)
#pragma unroll
            for (int mt = 0; mt < MH; ++mt)
                acc[nt][mt] = mfma16(w0f[ks][nt], x[mt], acc[nt][mt]);
    }
#pragma unroll
    for (int mt = 0; mt < MH; ++mt)
#pragma unroll
        for (int nt = 0; nt < 2; ++nt) {
            f16x4 h;
#pragma unroll
            for (int i = 0; i < 4; ++i) h[i] = (_Float16)fmaxf(acc[nt][mt][i], 0.f);
            *(f16x4*)(H0 + (mt * 16 + l16) * 136 + w * 32 + nt * 16 + q * 4) = h;
        }
    BAR();
    f32x4 a1[2][MH];
#pragma unroll
    for (int nt = 0; nt < 2; ++nt)
#pragma unroll
        for (int mt = 0; mt < MH; ++mt) a1[nt][mt] = zero;
#pragma unroll
    for (int ks = 0; ks < 4; ++ks) {
        f16x8 x[MH];
#pragma unroll
        for (int mt = 0; mt < MH; ++mt)
            x[mt] = *(const f16x8*)(H0 + (mt * 16 + l16) * 136 + ks * 32 + q * 8);
#pragma unroll
        for (int nt = 0; nt < 2; ++nt)
#pragma unroll
            for (int mt = 0; mt < MH; ++mt)
                a1[nt][mt] = mfma16(w1f[ks][nt], x[mt], a1[nt][mt]);
    }
#pragma unroll
    for (int mt = 0; mt < MH; ++mt)
#pragma unroll
        for (int nt = 0; nt < 2; ++nt) {
            f16x4 h;
#pragma unroll
            for (int i = 0; i < 4; ++i) h[i] = (_Float16)fmaxf(a1[nt][mt][i], 0.f);
            *(f16x4*)(H1 + (mt * 16 + l16) * 136 + w * 32 + nt * 16 + q * 4) = h;
        }
    BAR();
}

// Layer 2, row group g: rows (w>>1)*16 + l16 + 32*g, cols (w&1)*16 + q*4 + i.
DI f32x4 l2g(const f16x8* w2f, const _Float16* __restrict__ H1, int l16, int w,
             int q, int g) {
    int m = (w >> 1) * 16 + l16 + 32 * g;
    f32x4 acc = {0.f, 0.f, 0.f, 0.f};
#pragma unroll
    for (int ks = 0; ks < 4; ++ks) {
        f16x8 x = *(const f16x8*)(H1 + m * 136 + ks * 32 + q * 8);
        acc = mfma16(w2f[ks], x, acc);
    }
    return acc;
}

// ---------------- weight prep: fp32 [K][N] -> f16 W^T [Np][Kp] (zero padded) ----
// Blocks 33..157 additionally zero the CSR cursor (fused former k_zero).
struct WPtrs { const float* p[15]; };

__global__ void k_prep(WPtrs wp, _Float16* __restrict__ ws,
                       unsigned* __restrict__ cursor) {
    int b = blockIdx.x;
    if (b >= 33) {
        int i = (b - 33) * 256 + threadIdx.x;
        if (i < 32000) cursor[i] = 0u;
        return;
    }
    const float* src; int K, N, Np, Kp, off;
    if (b == 0)       { src = wp.p[0];  K = 3;   N = 128; Np = 128; Kp = 32;  off = 0; }
    else if (b == 1)  { src = wp.p[1];  K = 128; N = 128; Np = 128; Kp = 128; off = 4096; }
    else if (b == 2)  { src = wp.p[2];  K = 128; N = 32;  Np = 32;  Kp = 128; off = 20480; }
    else if (b == 3)  { src = wp.p[3];  K = 3;   N = 128; Np = 128; Kp = 32;  off = 24576; }
    else if (b == 4)  { src = wp.p[4];  K = 128; N = 128; Np = 128; Kp = 128; off = 28672; }
    else if (b == 5)  { src = wp.p[5];  K = 128; N = 32;  Np = 32;  Kp = 128; off = 45056; }
    else if (b <= 9)  { int t = b - 6;  src = wp.p[6] + t * 12288;  K = 96;  N = 128; Np = 128; Kp = 96;  off = 49152 + t * 32768; }
    else if (b <= 13) { int t = b - 10; src = wp.p[7] + t * 16384;  K = 128; N = 128; Np = 128; Kp = 128; off = 61440 + t * 32768; }
    else if (b <= 17) { int t = b - 14; src = wp.p[8] + t * 4096;   K = 128; N = 32;  Np = 32;  Kp = 128; off = 77824 + t * 32768; }
    else if (b <= 21) { int t = b - 18; src = wp.p[9] + t * 8192;   K = 64;  N = 128; Np = 128; Kp = 64;  off = 180224 + t * 28672; }
    else if (b <= 25) { int t = b - 22; src = wp.p[10] + t * 16384; K = 128; N = 128; Np = 128; Kp = 128; off = 188416 + t * 28672; }
    else if (b <= 29) { int t = b - 26; src = wp.p[11] + t * 4096;  K = 128; N = 32;  Np = 32;  Kp = 128; off = 204800 + t * 28672; }
    else if (b == 30) { src = wp.p[12]; K = 32;  N = 128; Np = 128; Kp = 32;  off = 294912; }
    else if (b == 31) { src = wp.p[13]; K = 128; N = 128; Np = 128; Kp = 128; off = 299008; }
    else              { src = wp.p[14]; K = 128; N = 1;   Np = 16;  Kp = 128; off = 315392; }
    int total = Np * Kp;
    for (int i = threadIdx.x; i < total; i += 256) {
        int n = i / Kp, k = i - n * Kp;
        float v = (k < K && n < N) ? src[k * N + n] : 0.f;
        ws[off + i] = (_Float16)v;
    }
}

// ---------------- CSR build: histogram -> scan -> scatter (u32 atomics only) -----
__global__ void k_hist(const int* __restrict__ gi, unsigned* __restrict__ cnt) {
    int e = blockIdx.x * 256 + threadIdx.x;
    if (e < 512000) atomicAdd(&cnt[gi[2 * e + 1]], 1u);
}
// one block, 1024 threads: exclusive scan of cnt[0..32000).
// All global accesses are stride-1024 coalesced; per-thread contiguous work
// happens in LDS (R17 lesson: the old direct version's 128-B-strided lane
// pattern cost ~50 us on a single CU).
__global__ __launch_bounds__(1024) void k_scan(
    const unsigned* __restrict__ cnt, unsigned* __restrict__ rowptr,
    unsigned* __restrict__ cursor) {
    __shared__ unsigned sv[32000];   // 128,000 B (fits gfx950's 160 KB LDS)
    __shared__ unsigned s[1024];
    int t = threadIdx.x;
    for (int i = t; i < 32000; i += 1024) sv[i] = cnt[i];
    __syncthreads();
    unsigned sum = 0;
#pragma unroll
    for (int i = 0; i < 32; ++i) {
        int idx = t * 32 + i;
        if (idx < 32000) sum += sv[idx];
    }
    s[t] = sum;
    __syncthreads();
#pragma unroll
    for (int d = 1; d < 1024; d <<= 1) {
        unsigned x = (t >= d) ? s[t - d] : 0u;
        __syncthreads();
        s[t] += x;
        __syncthreads();
    }
    if (t == 1023) rowptr[32000] = s[1023];
    unsigned off = (t == 0) ? 0u : s[t - 1];
#pragma unroll
    for (int i = 0; i < 32; ++i) {
        int idx = t * 32 + i;
        if (idx < 32000) { unsigned v = sv[idx]; sv[idx] = off; off += v; }
    }
    __syncthreads();
    for (int i = t; i < 32000; i += 1024) {
        unsigned v = sv[i];
        rowptr[i] = v;
        cursor[i] = v;
    }
}
// sr packed as u32: sender | (receiver<<16); both indices < 32000 < 2^16.
__global__ void k_scatter(const int* __restrict__ gi, unsigned* __restrict__ cursor,
                          unsigned* __restrict__ iperm, unsigned* __restrict__ sr) {
    int e = blockIdx.x * 256 + threadIdx.x;
    if (e < 512000) {
        int s = gi[2 * e], r = gi[2 * e + 1];
        unsigned pos = atomicAdd(&cursor[r], 1u);
        iperm[pos] = (unsigned)e;
        sr[pos] = (unsigned)s | ((unsigned)r << 16);
    }
}

// ---------------- fused encoder: nodes (blocks <500) + edges (blocks >=500) -----
// fp32 [M][3] -> MLP(32p->128->128->32) -> f16 out rows (64-row tiles).
__global__ __launch_bounds__(256, 3) void k_enc2(
    const float* __restrict__ in_n, _Float16* __restrict__ out_n,
    const float* __restrict__ in_e, _Float16* __restrict__ out_e,
    const unsigned* __restrict__ iperm,
    const _Float16* __restrict__ nw0, const _Float16* __restrict__ nw1,
    const _Float16* __restrict__ nw2,
    const _Float16* __restrict__ ew0, const _Float16* __restrict__ ew1,
    const _Float16* __restrict__ ew2) {
    __shared__ __align__(16) _Float16 Xp[64 * 40];
    __shared__ __align__(16) _Float16 H0[64 * 136];
    __shared__ __align__(16) _Float16 H1[64 * 136];
    const bool isNode = blockIdx.x < 500;
    const float* in = isNode ? in_n : in_e;
    _Float16* out = isNode ? out_n : out_e;
    const _Float16* w0t = isNode ? nw0 : ew0;
    const _Float16* w1t = isNode ? nw1 : ew1;
    const _Float16* w2t = isNode ? nw2 : ew2;
    const unsigned* ip = isNode ? nullptr : iperm;
    const int NT = isNode ? 500 : 8000;
    const int g = isNode ? 500 : 768;
    int t = isNode ? blockIdx.x : blockIdx.x - 500;

    const int tid = threadIdx.x, w = tid >> 6, lane = tid & 63;
    const int q = lane >> 4, l16 = lane & 15;
    f16x8 w0f[1][2], w1f[4][2], w2f[4];
    load_wf2<1>(w0t, 32, w * 32, l16, q, w0f);
    load_wf2<4>(w1t, 128, w * 32, l16, q, w1f);
    {
        int n2 = (w & 1) * 16 + l16;
#pragma unroll
        for (int ks = 0; ks < 4; ++ks)
            w2f[ks] = *(const f16x8*)(w2t + n2 * 128 + ks * 32 + q * 8);
    }
    for (int c = tid; c < 2560; c += 256) Xp[c] = (_Float16)0.f;
    BAR();

    const int dr = tid / 3, dc = tid - dr * 3;  // valid when tid<192
    const int orow = (w >> 1) * 16 + l16, ocol = (w & 1) * 16 + q * 4;

    while (true) {
        if (tid < 192) {
            unsigned e = ip ? ip[t * 64 + dr] : (unsigned)(t * 64 + dr);
            Xp[dr * 40 + dc] = (_Float16)in[e * 3 + dc];
        }
        BAR();
        l01<1, 4>(w0f, w1f, Xp, 40, H0, H1, l16, w, q);
#pragma unroll
        for (int gg = 0; gg < 2; ++gg) {
            f32x4 o = l2g(w2f, H1, l16, w, q, gg);
            f16x4 ov;
#pragma unroll
            for (int i = 0; i < 4; ++i) ov[i] = (_Float16)o[i];
            *(f16x4*)(out + (t * 64 + gg * 32 + orow) * 32 + ocol) = ov;
        }
        t += g;
        if (t >= NT) break;
    }
}

// ---------------- edge update: [edge|node_s|node_r](96) -> MLP -> +res -----------
// R13-proven: 64-row tiles, register staging (gather -> ds_write), packed-u32 sr
// prefetched one tile ahead, residual's old value read from LDS post-barrier.
__global__ __launch_bounds__(256, 3) void k_edge(
    const _Float16* __restrict__ node, _Float16* __restrict__ edgeP,
    const unsigned* __restrict__ sr,
    const _Float16* __restrict__ w0t, const _Float16* __restrict__ w1t,
    const _Float16* __restrict__ w2t) {
    __shared__ __align__(16) _Float16 Xe[64 * 104];
    __shared__ __align__(16) _Float16 H0[64 * 136];
    __shared__ __align__(16) _Float16 H1[64 * 136];
    const int tid = threadIdx.x, w = tid >> 6, lane = tid & 63;
    const int q = lane >> 4, l16 = lane & 15;
    f16x8 w0f[3][2], w1f[4][2], w2f[4];
    load_wf2<3>(w0t, 96, w * 32, l16, q, w0f);
    load_wf2<4>(w1t, 128, w * 32, l16, q, w1f);
    {
        int n2 = (w & 1) * 16 + l16;
#pragma unroll
        for (int ks = 0; ks < 4; ++ks)
            w2f[ks] = *(const f16x8*)(w2t + n2 * 128 + ks * 32 + q * 8);
    }
    int cr[3], cs[3];
#pragma unroll
    for (int j = 0; j < 3; ++j) {
        int c = tid + 256 * j;
        cr[j] = c / 12; cs[j] = c - cr[j] * 12;
    }
    const int orow = (w >> 1) * 16 + l16, ocol = (w & 1) * 16 + q * 4;

    const int NT = 8000, g = gridDim.x;
    int t = blockIdx.x;
    unsigned srv[3];
#pragma unroll
    for (int j = 0; j < 3; ++j) srv[j] = sr[t * 64 + cr[j]];

    while (true) {
        int tn = t + g; if (tn >= NT) tn = t;
        // stage tile t (loads issue; Xe write waits on them via vmcnt)
        int4 v[3];
#pragma unroll
        for (int j = 0; j < 3; ++j) {
            int s = cs[j];
            const _Float16* src = (s < 4) ? edgeP + (t * 64 + cr[j]) * 32 + s * 8
                               : (s < 8) ? node + (srv[j] & 0xffffu) * 32 + (s - 4) * 8
                                         : node + (srv[j] >> 16) * 32 + (s - 8) * 8;
            v[j] = *(const int4*)src;
        }
        unsigned srn[3];
#pragma unroll
        for (int j = 0; j < 3; ++j) srn[j] = sr[tn * 64 + cr[j]];
#pragma unroll
        for (int j = 0; j < 3; ++j)
            *(int4*)(Xe + cr[j] * 104 + cs[j] * 8) = v[j];
        BAR();
        // old edge latent from LDS (cols 0..31 of the staged tile)
        f16x4 oldv[2];
#pragma unroll
        for (int gg = 0; gg < 2; ++gg)
            oldv[gg] = *(const f16x4*)(Xe + (gg * 32 + orow) * 104 + ocol);

        l01<3, 4>(w0f, w1f, Xe, 104, H0, H1, l16, w, q);
#pragma unroll
        for (int gg = 0; gg < 2; ++gg) {
            f32x4 o = l2g(w2f, H1, l16, w, q, gg);
            f16x4 nv;
#pragma unroll
            for (int i = 0; i < 4; ++i) nv[i] = (_Float16)(o[i] + (float)oldv[gg][i]);
            *(f16x4*)(edgeP + (t * 64 + gg * 32 + orow) * 32 + ocol) = nv;
        }

        if (tn == t) break;
        t = tn;
#pragma unroll
        for (int j = 0; j < 3; ++j) srv[j] = srn[j];
    }
}

// ---------------- node update: [node|csr_sum(edgeP)](64) -> MLP -> +res ----------
// Proven 32-row data path; 2-iteration grid-stride loop (verified R15-R17).
__global__ __launch_bounds__(256, 3) void k_node(
    _Float16* __restrict__ node, const _Float16* __restrict__ edgeP,
    const unsigned* __restrict__ rowptr,
    const _Float16* __restrict__ w0t, const _Float16* __restrict__ w1t,
    const _Float16* __restrict__ w2t) {
    __shared__ __align__(16) _Float16 Xn[32 * 72];
    __shared__ __align__(16) _Float16 H0[32 * 136];
    __shared__ __align__(16) _Float16 H1[32 * 136];
    const int tid = threadIdx.x, w = tid >> 6, lane = tid & 63;
    const int q = lane >> 4, l16 = lane & 15;
    f16x8 w0f[2][2], w1f[4][2], w2f[4];
    load_wf2<2>(w0t, 64, w * 32, l16, q, w0f);
    load_wf2<4>(w1t, 128, w * 32, l16, q, w1f);
    {
        int n2 = (w & 1) * 16 + l16;
#pragma unroll
        for (int ks = 0; ks < 4; ++ks)
            w2f[ks] = *(const f16x8*)(w2t + n2 * 128 + ks * 32 + q * 8);
    }
    const int orow = (w >> 1) * 16 + l16, ocol = (w & 1) * 16 + q * 4;
    const int g = gridDim.x;
    for (int t = blockIdx.x; t < 1000; t += g) {
        // 8 chunks/row (16 B each): cs<4 node copy, cs>=4 segment-sum of edgeP chunk
        {
            int cr = tid >> 3, cs = tid & 7;
            int r = t * 32 + cr;
            if (cs < 4) {
                *(int4*)(Xn + cr * 72 + cs * 8) = *(const int4*)(node + r * 32 + cs * 8);
            } else {
                unsigned b = rowptr[r], e = rowptr[r + 1];
                const _Float16* base = edgeP + (cs - 4) * 8;
                float a0[8], a1[8];
#pragma unroll
                for (int i = 0; i < 8; ++i) { a0[i] = 0.f; a1[i] = 0.f; }
                unsigned p = b;
                for (; p + 2 <= e; p += 2) {
                    f16x8 x0 = *(const f16x8*)(base + (p + 0) * 32);
                    f16x8 x1 = *(const f16x8*)(base + (p + 1) * 32);
#pragma unroll
                    for (int i = 0; i < 8; ++i) { a0[i] += (float)x0[i]; a1[i] += (float)x1[i]; }
                }
                if (p < e) {
                    f16x8 x0 = *(const f16x8*)(base + p * 32);
#pragma unroll
                    for (int i = 0; i < 8; ++i) a0[i] += (float)x0[i];
                }
                f16x8 h;
#pragma unroll
                for (int i = 0; i < 8; ++i) h[i] = (_Float16)(a0[i] + a1[i]);
                *(f16x8*)(Xn + cr * 72 + cs * 8) = h;
            }
        }
        BAR();
        f16x4 oldv = *(const f16x4*)(Xn + orow * 72 + ocol);
        l01<2, 2>(w0f, w1f, Xn, 72, H0, H1, l16, w, q);
        f32x4 o = l2g(w2f, H1, l16, w, q, 0);
        f16x4 nv;
#pragma unroll
        for (int i = 0; i < 4; ++i) nv[i] = (_Float16)(o[i] + (float)oldv[i]);
        *(f16x4*)(node + (t * 32 + orow) * 32 + ocol) = nv;
    }
}

// ---------------- decoder: node(32) -> MLP(32->128->128->1) -> fp32 out ----------
__global__ __launch_bounds__(256, 3) void k_dec(
    const _Float16* __restrict__ node,
    const _Float16* __restrict__ w0t, const _Float16* __restrict__ w1t,
    const _Float16* __restrict__ w2t, float* __restrict__ out) {
    __shared__ __align__(16) _Float16 Xd[64 * 40];
    __shared__ __align__(16) _Float16 H0[64 * 136];
    __shared__ __align__(16) _Float16 H1[64 * 136];
    const int tid = threadIdx.x, w = tid >> 6, lane = tid & 63;
    const int q = lane >> 4, l16 = lane & 15;
    f16x8 w0f[1][2], w1f[4][2], w2f[4];
    load_wf2<1>(w0t, 32, w * 32, l16, q, w0f);
    load_wf2<4>(w1t, 128, w * 32, l16, q, w1f);
    {
        int n2 = l16;  // padded W2^T is [16][128]; all waves load tile 0
#pragma unroll
        for (int ks = 0; ks < 4; ++ks)
            w2f[ks] = *(const f16x8*)(w2t + n2 * 128 + ks * 32 + q * 8);
    }
    const int t = blockIdx.x;
    {
        int cr = tid >> 2, cs = tid & 3;
        *(int4*)(Xd + cr * 40 + cs * 8) = *(const int4*)(node + (t * 64 + cr) * 32 + cs * 8);
    }
    BAR();
    l01<1, 4>(w0f, w1f, Xd, 40, H0, H1, l16, w, q);
#pragma unroll
    for (int gg = 0; gg < 2; ++gg) {
        f32x4 o = l2g(w2f, H1, l16, w, q, gg);
        // only col 0 is real: waves with (w&1)==0, lanes q==0, reg 0
        if ((w & 1) == 0 && q == 0) out[t * 64 + gg * 32 + (w >> 1) * 16 + l16] = o[0];
    }
}

extern "C" void kernel_launch(void* const* d_in, const int* in_sizes, int n_in,
                              void* d_out, int out_size, void* d_ws, size_t ws_size,
                              hipStream_t stream) {
    const float* input_node = (const float*)d_in[0];
    const float* input_edge = (const float*)d_in[1];
    const int* gi = (const int*)d_in[2];

    _Float16* ws = (_Float16*)d_ws;
    // ws layout (bytes):
    //   weights f16:         [0,          634,880)
    //   node  f16 32000x32:  [655,360,    2,703,360)
    //   edgeP f16 512000x32: [2,703,360,  35,471,360)   (receiver-sorted rows)
    //   rowptr u32[32001]:   [35,471,360, 35,599,364)
    //   cursor u32[32000]:   [35,599,616, 35,727,616)
    //   iperm  u32[512000]:  [35,727,616, 37,775,616)
    //   sr     u32[512000]:  [37,775,616, 39,823,616)   (sender | receiver<<16)
    _Float16* node = (_Float16*)((char*)d_ws + 655360);
    _Float16* edgeP = (_Float16*)((char*)d_ws + 2703360);
    unsigned* rowptr = (unsigned*)((char*)d_ws + 35471360);
    unsigned* cursor = (unsigned*)((char*)d_ws + 35599616);
    unsigned* iperm = (unsigned*)((char*)d_ws + 35727616);
    unsigned* sr = (unsigned*)((char*)d_ws + 37775616);

    WPtrs wp;
    for (int i = 0; i < 15; ++i) wp.p[i] = (const float*)d_in[3 + i];

    // weight prep + cursor zero (fused)
    k_prep<<<158, 256, 0, stream>>>(wp, ws, cursor);

    // CSR build (u32 atomics only)
    k_hist<<<2000, 256, 0, stream>>>(gi, cursor);
    k_scan<<<1, 1024, 0, stream>>>(cursor, rowptr, cursor);
    k_scatter<<<2000, 256, 0, stream>>>(gi, cursor, iperm, sr);

    // fused encoder: blocks <500 encode nodes, blocks >=500 encode edges
    k_enc2<<<1268, 256, 0, stream>>>(input_node, node, input_edge, edgeP, iperm,
                                     ws + 0, ws + 4096, ws + 20480,
                                     ws + 24576, ws + 28672, ws + 45056);

    for (int t = 0; t < 4; ++t) {
        k_edge<<<768, 256, 0, stream>>>(node, edgeP, sr,
                                        ws + 49152 + t * 32768,
                                        ws + 61440 + t * 32768,
                                        ws + 77824 + t * 32768);
        k_node<<<500, 256, 0, stream>>>(node, edgeP, rowptr,
                                        ws + 180224 + t * 28672,
                                        ws + 188416 + t * 28672,
                                        ws + 204800 + t * 28672);
    }
    k_dec<<<500, 256, 0, stream>>>(node, ws + 294912, ws + 299008, ws + 315392,
                                   (float*)d_out);
}